// Round 1
// baseline (247.488 us; speedup 1.0000x reference)
//
#include <hip/hip_runtime.h>

typedef __attribute__((ext_vector_type(8))) __bf16 bf16x8;
typedef __attribute__((ext_vector_type(4))) float f32x4;
typedef unsigned short u16;

#define DEV static __device__ __forceinline__

DEV void gload_lds16(const void* g, void* l) {
  __builtin_amdgcn_global_load_lds((const __attribute__((address_space(1))) void*)g,
                                   (__attribute__((address_space(3))) void*)l, 16, 0, 0);
}

// ---------------- convert x -> bf16 ----------------
__global__ void cvt_kernel(const float* __restrict__ src, __bf16* __restrict__ dst, int n) {
  int i = (blockIdx.x * 256 + threadIdx.x) * 8;
  if (i >= n) return;
  float4 a = *(const float4*)(src + i);
  float4 b = *(const float4*)(src + i + 4);
  bf16x8 o;
  o[0] = (__bf16)a.x; o[1] = (__bf16)a.y; o[2] = (__bf16)a.z; o[3] = (__bf16)a.w;
  o[4] = (__bf16)b.x; o[5] = (__bf16)b.y; o[6] = (__bf16)b.z; o[7] = (__bf16)b.w;
  *(bf16x8*)(dst + i) = o;
}

// ------------- transpose + convert weights: src K x N (f32) -> dst N x K (bf16) -------------
__global__ void tcvt_kernel(const float* __restrict__ src, __bf16* __restrict__ dst, int K, int N) {
  __shared__ float tile[32][33];
  int k0 = blockIdx.y * 32, n0 = blockIdx.x * 32;
  int tx = threadIdx.x & 31, ty = threadIdx.x >> 5;  // ty 0..7
  #pragma unroll
  for (int i = 0; i < 32; i += 8)
    tile[ty + i][tx] = src[(size_t)(k0 + ty + i) * N + n0 + tx];
  __syncthreads();
  #pragma unroll
  for (int i = 0; i < 32; i += 8)
    dst[(size_t)(n0 + ty + i) * K + k0 + tx] = (__bf16)tile[tx][ty + i];
}

// ---------------- GEMM: C[MxN] = A[MxK] @ Bt[NxK]^T, bf16 in, OutT out ----------------
#define BM 128
#define BN 128
#define BKK 32

template <typename OutT>
__global__ __launch_bounds__(256, 2) void gemm_bt(const __bf16* __restrict__ A,
                                                  const __bf16* __restrict__ Bt,
                                                  OutT* __restrict__ C, int M, int N, int K) {
  __shared__ __bf16 As[2][BM * BKK];
  __shared__ __bf16 Bs[2][BM * BKK];
  const int tid = threadIdx.x;
  const int l = tid & 63;
  const int wid = tid >> 6;
  const int wr = wid >> 1, wc = wid & 1;
  const int brow = blockIdx.y * BM, bcol = blockIdx.x * BN;
  const int g = l >> 4, ln = l & 15;

  f32x4 acc[4][4] = {};

  const int NT = K / BKK;

  auto stage = [&](int buf, int kt) {
    #pragma unroll
    for (int i = 0; i < 2; ++i) {
      int row = i * 64 + (tid >> 2);
      int kk = (tid & 3) * 8;
      int kksw = kk ^ (((row >> 1) & 3) * 8);  // source pre-swizzle
      gload_lds16(A + (size_t)(brow + row) * K + kt * BKK + kksw,
                  (char*)&As[buf][0] + i * 4096 + tid * 16);
      gload_lds16(Bt + (size_t)(bcol + row) * K + kt * BKK + kksw,
                  (char*)&Bs[buf][0] + i * 4096 + tid * 16);
    }
  };

  stage(0, 0);
  int cur = 0;
  for (int t = 0; t < NT; ++t) {
    __syncthreads();  // staged buf[cur] ready (drains vmcnt)
    if (t + 1 < NT) stage(cur ^ 1, t + 1);
    bf16x8 af[4], bfr[4];
    #pragma unroll
    for (int m = 0; m < 4; ++m) {
      int row = wr * 64 + m * 16 + ln;
      af[m] = *(const bf16x8*)((const char*)&As[cur][0] + row * 64 +
                               ((g * 8) ^ (((row >> 1) & 3) * 8)) * 2);
    }
    #pragma unroll
    for (int n = 0; n < 4; ++n) {
      int row = wc * 64 + n * 16 + ln;
      bfr[n] = *(const bf16x8*)((const char*)&Bs[cur][0] + row * 64 +
                                ((g * 8) ^ (((row >> 1) & 3) * 8)) * 2);
    }
    #pragma unroll
    for (int m = 0; m < 4; ++m)
      #pragma unroll
      for (int n = 0; n < 4; ++n)
        acc[m][n] = __builtin_amdgcn_mfma_f32_16x16x32_bf16(af[m], bfr[n], acc[m][n], 0, 0, 0);
    cur ^= 1;
  }
  // epilogue: C/D layout col=lane&15, row=(lane>>4)*4+j  [m89-verified]
  #pragma unroll
  for (int m = 0; m < 4; ++m)
    #pragma unroll
    for (int n = 0; n < 4; ++n)
      #pragma unroll
      for (int j = 0; j < 4; ++j) {
        size_t r = brow + wr * 64 + m * 16 + g * 4 + j;
        size_t c = bcol + wc * 64 + n * 16 + ln;
        C[r * N + c] = (OutT)acc[m][n][j];
      }
}

// ---------------- RoPE in place on QKV buffer [4096][3072] ----------------
__global__ void rope_kernel(__bf16* __restrict__ QKV, const float* __restrict__ cosb,
                            const float* __restrict__ sinb) {
  int gid = blockIdx.x * 256 + threadIdx.x;  // total 4096*20*16
  int p = gid & 15;
  int ht = gid >> 4;
  int hc = ht % 20;
  int tok = ht / 20;
  int s = tok & 1023;
  int colb = hc < 16 ? hc * 128 : 2048 + (hc - 16) * 128;
  __bf16* base = QKV + (size_t)tok * 3072 + colb;
  int d0 = p * 4;
  const float* cr = cosb + s * 128;
  const float* sr = sinb + s * 128;
  float x0[4], x1[4];
  #pragma unroll
  for (int j = 0; j < 4; ++j) {
    x0[j] = (float)base[d0 + j];
    x1[j] = (float)base[d0 + 64 + j];
  }
  #pragma unroll
  for (int j = 0; j < 4; ++j) {
    float n0 = x0[j] * cr[d0 + j] - x1[j] * sr[d0 + j];
    float n1 = x1[j] * cr[d0 + 64 + j] + x0[j] * sr[d0 + 64 + j];
    base[d0 + j] = (__bf16)n0;
    base[d0 + 64 + j] = (__bf16)n1;
  }
}

// ---------------- Flash attention (causal, GQA) ----------------
// QKV [4096][3072] bf16 (q: cols 0..2047 = h*128+d, k: 2048..2559, v: 2560..3071)
// AO  [4096][2048] bf16
__global__ __launch_bounds__(256, 2) void attn_kernel(const __bf16* __restrict__ QKV,
                                                      __bf16* __restrict__ AO) {
  __shared__ __bf16 Kl[64 * 128];    // swizzled: [r][d ^ ((r&7)*8)]
  __shared__ __bf16 Vlin[64 * 128];  // linear
  __shared__ __bf16 Vt[128 * 72];    // V^T padded, [d][s]
  __shared__ __bf16 Pl[4][16 * 72];  // per-wave P

  const int tid = threadIdx.x, l = tid & 63, w = tid >> 6;
  const int qt = blockIdx.x, h = blockIdx.y, b = blockIdx.z;
  const int kvh = h >> 2;
  const int g = l >> 4, ln = l & 15;
  const size_t tokQ = (size_t)b * 1024 + qt * 64;

  // Q fragments (A layout: row = lane&15, k = (lane>>4)*8+j)
  bf16x8 qf[4];
  {
    const __bf16* qp = QKV + (tokQ + w * 16 + ln) * 3072 + h * 128;
    #pragma unroll
    for (int ks = 0; ks < 4; ++ks) qf[ks] = *(const bf16x8*)(qp + ks * 32 + g * 8);
  }

  float mrow[4], lrow[4];
  f32x4 acco[8] = {};
  #pragma unroll
  for (int j = 0; j < 4; ++j) { mrow[j] = -1e30f; lrow[j] = 0.f; }

  auto stage = [&](int kt) {
    const size_t tokK = (size_t)b * 1024 + kt * 64;
    #pragma unroll
    for (int i = 0; i < 4; ++i) {
      int r = i * 16 + (tid >> 4);
      int d0 = (tid & 15) * 8;
      int d0s = d0 ^ ((r & 7) * 8);
      gload_lds16(QKV + (tokK + r) * 3072 + 2048 + kvh * 128 + d0s,
                  (char*)Kl + i * 4096 + tid * 16);
      gload_lds16(QKV + (tokK + r) * 3072 + 2560 + kvh * 128 + d0,
                  (char*)Vlin + i * 4096 + tid * 16);
    }
  };

  stage(0);
  for (int kt = 0; kt <= qt; ++kt) {
    __syncthreads();  // A: stage complete
    // transpose V: Vlin[s][d] -> Vt[d][s], stride 72
    #pragma unroll
    for (int c = 0; c < 4; ++c) {
      int tau = tid + 256 * c;
      int d = tau & 127, s0 = (tau >> 7) * 8;
      bf16x8 tv;
      #pragma unroll
      for (int j = 0; j < 8; ++j) tv[j] = Vlin[(s0 + j) * 128 + d];
      *(bf16x8*)((char*)Vt + d * 144 + s0 * 2) = tv;
    }
    // QK^T
    f32x4 accs[4] = {};
    #pragma unroll
    for (int cb = 0; cb < 4; ++cb) {
      int n = cb * 16 + ln;
      #pragma unroll
      for (int ks = 0; ks < 4; ++ks) {
        bf16x8 kb = *(const bf16x8*)((const char*)Kl + n * 256 +
                                     (((ks * 4 + g) * 8) ^ ((n & 7) * 8)) * 2);
        accs[cb] = __builtin_amdgcn_mfma_f32_16x16x32_bf16(qf[ks], kb, accs[cb], 0, 0, 0);
      }
    }
    // scale + causal mask
    const float sc = 0.08838834764831845f;  // 1/sqrt(128)
    #pragma unroll
    for (int cb = 0; cb < 4; ++cb)
      #pragma unroll
      for (int j = 0; j < 4; ++j) {
        float s = accs[cb][j] * sc;
        if (kt == qt) {
          int colt = cb * 16 + ln, rowt = w * 16 + g * 4 + j;
          if (colt > rowt) s = -1e30f;
        }
        accs[cb][j] = s;
      }
    // online softmax (rows live across ln lanes; reduce over 16-lane group)
    float mt[4];
    #pragma unroll
    for (int j = 0; j < 4; ++j)
      mt[j] = fmaxf(fmaxf(accs[0][j], accs[1][j]), fmaxf(accs[2][j], accs[3][j]));
    #pragma unroll
    for (int x = 1; x < 16; x <<= 1)
      #pragma unroll
      for (int j = 0; j < 4; ++j) mt[j] = fmaxf(mt[j], __shfl_xor(mt[j], x, 64));
    float corr[4], mnew[4];
    #pragma unroll
    for (int j = 0; j < 4; ++j) {
      mnew[j] = fmaxf(mrow[j], mt[j]);
      corr[j] = __expf(mrow[j] - mnew[j]);
      mrow[j] = mnew[j];
    }
    float rs[4] = {0.f, 0.f, 0.f, 0.f};
    #pragma unroll
    for (int cb = 0; cb < 4; ++cb)
      #pragma unroll
      for (int j = 0; j < 4; ++j) {
        float p = __expf(accs[cb][j] - mnew[j]);
        accs[cb][j] = p;
        rs[j] += p;
      }
    #pragma unroll
    for (int x = 1; x < 16; x <<= 1)
      #pragma unroll
      for (int j = 0; j < 4; ++j) rs[j] += __shfl_xor(rs[j], x, 64);
    #pragma unroll
    for (int j = 0; j < 4; ++j) lrow[j] = lrow[j] * corr[j] + rs[j];
    #pragma unroll
    for (int n = 0; n < 8; ++n)
      #pragma unroll
      for (int j = 0; j < 4; ++j) acco[n][j] *= corr[j];
    // P -> LDS (per wave)
    {
      __bf16* Pw = &Pl[w][0];
      #pragma unroll
      for (int cb = 0; cb < 4; ++cb)
        #pragma unroll
        for (int j = 0; j < 4; ++j) Pw[(g * 4 + j) * 72 + cb * 16 + ln] = (__bf16)accs[cb][j];
    }
    __syncthreads();  // B: Vt + P visible; Kl/Vlin reads done
    if (kt + 1 <= qt) stage(kt + 1);  // overlap next stage with PV
    // PV
    #pragma unroll
    for (int ks2 = 0; ks2 < 2; ++ks2) {
      bf16x8 pa = *(const bf16x8*)((const char*)&Pl[w][0] + ln * 144 + (ks2 * 32 + g * 8) * 2);
      #pragma unroll
      for (int n = 0; n < 8; ++n) {
        bf16x8 vb = *(const bf16x8*)((const char*)Vt + (n * 16 + ln) * 144 + (ks2 * 32 + g * 8) * 2);
        acco[n] = __builtin_amdgcn_mfma_f32_16x16x32_bf16(pa, vb, acco[n], 0, 0, 0);
      }
    }
  }
  // epilogue
  float rl[4];
  #pragma unroll
  for (int j = 0; j < 4; ++j) rl[j] = 1.f / lrow[j];
  #pragma unroll
  for (int n = 0; n < 8; ++n)
    #pragma unroll
    for (int j = 0; j < 4; ++j) {
      size_t r = tokQ + w * 16 + g * 4 + j;
      AO[r * 2048 + h * 128 + n * 16 + ln] = (__bf16)(acco[n][j] * rl[j]);
    }
}

// ---------------- launch ----------------
extern "C" void kernel_launch(void* const* d_in, const int* in_sizes, int n_in,
                              void* d_out, int out_size, void* d_ws, size_t ws_size,
                              hipStream_t stream) {
  const float* x    = (const float*)d_in[0];
  const float* cosb = (const float*)d_in[1];
  const float* sinb = (const float*)d_in[2];
  const float* wq   = (const float*)d_in[3];
  const float* wk   = (const float*)d_in[4];
  const float* wv   = (const float*)d_in[5];
  const float* wo   = (const float*)d_in[6];
  float* out = (float*)d_out;

  char* ws = (char*)d_ws;
  const size_t OFF_XB    = 0;                       // 4096*2048 bf16 = 16 MiB
  const size_t OFF_WQKVT = OFF_XB + 16777216;       // 3072*2048 bf16 = 12 MiB
  const size_t OFF_WOT   = OFF_WQKVT + 12582912;    // 2048*2048 bf16 = 8 MiB
  const size_t OFF_QKV   = OFF_WOT + 8388608;       // 4096*3072 bf16 = 24 MiB
  const size_t OFF_AO    = OFF_QKV + 25165824;      // 4096*2048 bf16 = 16 MiB

  __bf16* Xb    = (__bf16*)(ws + OFF_XB);
  __bf16* WqkvT = (__bf16*)(ws + OFF_WQKVT);
  __bf16* WoT   = (__bf16*)(ws + OFF_WOT);
  __bf16* QKVb  = (__bf16*)(ws + OFF_QKV);
  __bf16* AOb   = (__bf16*)(ws + OFF_AO);

  // 1. convert x
  cvt_kernel<<<4096 * 2048 / 8 / 256, 256, 0, stream>>>(x, Xb, 4096 * 2048);
  // 2. transpose-convert weights
  tcvt_kernel<<<dim3(64, 64), 256, 0, stream>>>(wq, WqkvT, 2048, 2048);
  tcvt_kernel<<<dim3(16, 64), 256, 0, stream>>>(wk, WqkvT + (size_t)2048 * 2048, 2048, 512);
  tcvt_kernel<<<dim3(16, 64), 256, 0, stream>>>(wv, WqkvT + (size_t)2560 * 2048, 2048, 512);
  tcvt_kernel<<<dim3(64, 64), 256, 0, stream>>>(wo, WoT, 2048, 2048);
  // 3. QKV projection
  gemm_bt<__bf16><<<dim3(3072 / BN, 4096 / BM), 256, 0, stream>>>(Xb, WqkvT, QKVb, 4096, 3072, 2048);
  // 4. RoPE in place (q + k)
  rope_kernel<<<4096 * 20 * 16 / 256, 256, 0, stream>>>(QKVb, cosb, sinb);
  // 5. attention
  attn_kernel<<<dim3(16, 16, 4), 256, 0, stream>>>(QKVb, AOb);
  // 6. output projection
  gemm_bt<float><<<dim3(2048 / BN, 4096 / BM), 256, 0, stream>>>(AOb, WoT, out, 4096, 2048, 2048);
}

// Round 4
// 230.259 us; speedup vs baseline: 1.0748x; 1.0748x over previous
//
#include <hip/hip_runtime.h>

typedef __attribute__((ext_vector_type(8))) __bf16 bf16x8;
typedef __attribute__((ext_vector_type(4))) float f32x4;

#define DEV static __device__ __forceinline__

DEV void gload_lds16(const void* g, void* l) {
  __builtin_amdgcn_global_load_lds((const __attribute__((address_space(1))) void*)g,
                                   (__attribute__((address_space(3))) void*)l, 16, 0, 0);
}

// ---------------- convert x -> bf16 ----------------
__global__ void cvt_kernel(const float* __restrict__ src, __bf16* __restrict__ dst, int n) {
  int i = (blockIdx.x * 256 + threadIdx.x) * 8;
  if (i >= n) return;
  float4 a = *(const float4*)(src + i);
  float4 b = *(const float4*)(src + i + 4);
  bf16x8 o;
  o[0] = (__bf16)a.x; o[1] = (__bf16)a.y; o[2] = (__bf16)a.z; o[3] = (__bf16)a.w;
  o[4] = (__bf16)b.x; o[5] = (__bf16)b.y; o[6] = (__bf16)b.z; o[7] = (__bf16)b.w;
  *(bf16x8*)(dst + i) = o;
}

// ------------- transpose + convert weights: src K x N (f32) -> dst N x K (bf16) -------------
__global__ void tcvt_kernel(const float* __restrict__ src, __bf16* __restrict__ dst, int K, int N) {
  __shared__ float tile[32][33];
  int k0 = blockIdx.y * 32, n0 = blockIdx.x * 32;
  int tx = threadIdx.x & 31, ty = threadIdx.x >> 5;  // ty 0..7
  #pragma unroll
  for (int i = 0; i < 32; i += 8)
    tile[ty + i][tx] = src[(size_t)(k0 + ty + i) * N + n0 + tx];
  __syncthreads();
  #pragma unroll
  for (int i = 0; i < 32; i += 8)
    dst[(size_t)(n0 + ty + i) * K + k0 + tx] = (__bf16)tile[tx][ty + i];
}

// ------------- transpose V out of QKV: VT[(b*4+kvh)*128 + d][s] = V[b*1024+s][kvh*128+d] -------------
__global__ void vt_kernel(const __bf16* __restrict__ QKV, __bf16* __restrict__ VT) {
  __shared__ __bf16 t[32][33];
  int sx = blockIdx.x;  // 0..31 s-tile within batch
  int dx = blockIdx.y;  // 0..3  d-tile
  int bk = blockIdx.z;  // 0..15 (b*4+kvh)
  int b = bk >> 2, kvh = bk & 3;
  int tx = threadIdx.x & 31, ty = threadIdx.x >> 5;
  #pragma unroll
  for (int i = 0; i < 32; i += 8)
    t[ty + i][tx] = QKV[(size_t)(b * 1024 + sx * 32 + ty + i) * 3072 + 2560 + kvh * 128 + dx * 32 + tx];
  __syncthreads();
  #pragma unroll
  for (int i = 0; i < 32; i += 8)
    VT[((size_t)bk * 128 + dx * 32 + ty + i) * 1024 + sx * 32 + tx] = t[tx][ty + i];
}

// ---------------- GEMM: C[MxN] = A[MxK] @ Bt[NxK]^T, bf16 in, OutT out ----------------
#define BM 128
#define BN 128
#define BKK 32

template <typename OutT>
__global__ __launch_bounds__(256, 2) void gemm_bt(const __bf16* __restrict__ A,
                                                  const __bf16* __restrict__ Bt,
                                                  OutT* __restrict__ C, int M, int N, int K) {
  __shared__ __bf16 As[2][BM * BKK];
  __shared__ __bf16 Bs[2][BM * BKK];
  const int tid = threadIdx.x;
  const int l = tid & 63;
  const int wid = tid >> 6;
  const int wr = wid >> 1, wc = wid & 1;
  const int brow = blockIdx.y * BM, bcol = blockIdx.x * BN;
  const int g = l >> 4, ln = l & 15;

  f32x4 acc[4][4] = {};

  const int NT = K / BKK;

  auto stage = [&](int buf, int kt) {
    #pragma unroll
    for (int i = 0; i < 2; ++i) {
      int row = i * 64 + (tid >> 2);
      int kk = (tid & 3) * 8;
      int kksw = kk ^ (((row >> 1) & 3) * 8);  // source pre-swizzle
      gload_lds16(A + (size_t)(brow + row) * K + kt * BKK + kksw,
                  (char*)&As[buf][0] + i * 4096 + tid * 16);
      gload_lds16(Bt + (size_t)(bcol + row) * K + kt * BKK + kksw,
                  (char*)&Bs[buf][0] + i * 4096 + tid * 16);
    }
  };

  stage(0, 0);
  int cur = 0;
  for (int t = 0; t < NT; ++t) {
    __syncthreads();  // staged buf[cur] ready (drains vmcnt)
    if (t + 1 < NT) stage(cur ^ 1, t + 1);
    bf16x8 af[4], bfr[4];
    #pragma unroll
    for (int m = 0; m < 4; ++m) {
      int row = wr * 64 + m * 16 + ln;
      af[m] = *(const bf16x8*)((const char*)&As[cur][0] + row * 64 +
                               ((g * 8) ^ (((row >> 1) & 3) * 8)) * 2);
    }
    #pragma unroll
    for (int n = 0; n < 4; ++n) {
      int row = wc * 64 + n * 16 + ln;
      bfr[n] = *(const bf16x8*)((const char*)&Bs[cur][0] + row * 64 +
                                ((g * 8) ^ (((row >> 1) & 3) * 8)) * 2);
    }
    #pragma unroll
    for (int m = 0; m < 4; ++m)
      #pragma unroll
      for (int n = 0; n < 4; ++n)
        acc[m][n] = __builtin_amdgcn_mfma_f32_16x16x32_bf16(af[m], bfr[n], acc[m][n], 0, 0, 0);
    cur ^= 1;
  }
  // epilogue: C/D layout col=lane&15, row=(lane>>4)*4+j  [m89-verified]
  #pragma unroll
  for (int m = 0; m < 4; ++m)
    #pragma unroll
    for (int n = 0; n < 4; ++n)
      #pragma unroll
      for (int j = 0; j < 4; ++j) {
        size_t r = brow + wr * 64 + m * 16 + g * 4 + j;
        size_t c = bcol + wc * 64 + n * 16 + ln;
        C[r * N + c] = (OutT)acc[m][n][j];
      }
}

// ---------------- RoPE in place on QKV buffer [4096][3072] ----------------
__global__ void rope_kernel(__bf16* __restrict__ QKV, const float* __restrict__ cosb,
                            const float* __restrict__ sinb) {
  int gid = blockIdx.x * 256 + threadIdx.x;  // total 4096*20*16
  int p = gid & 15;
  int ht = gid >> 4;
  int hc = ht % 20;
  int tok = ht / 20;
  int s = tok & 1023;
  int colb = hc < 16 ? hc * 128 : 2048 + (hc - 16) * 128;
  __bf16* base = QKV + (size_t)tok * 3072 + colb;
  int d0 = p * 4;
  const float* cr = cosb + s * 128;
  const float* sr = sinb + s * 128;
  float x0[4], x1[4];
  #pragma unroll
  for (int j = 0; j < 4; ++j) {
    x0[j] = (float)base[d0 + j];
    x1[j] = (float)base[d0 + 64 + j];
  }
  #pragma unroll
  for (int j = 0; j < 4; ++j) {
    float n0 = x0[j] * cr[d0 + j] - x1[j] * sr[d0 + j];
    float n1 = x1[j] * cr[d0 + 64 + j] + x0[j] * sr[d0 + 64 + j];
    base[d0 + j] = (__bf16)n0;
    base[d0 + 64 + j] = (__bf16)n1;
  }
}

// ---------------- Flash attention (causal, GQA) ----------------
// QKV [4096][3072] bf16 (q: cols 0..2047, k: 2048..2559).  VT [16*128][1024] bf16 (pre-transposed V).
// AO  [4096][2048] bf16
// Q tile = 128 rows (4 waves x 32), KV tile = 64.
// K  LDS: [64 r][128 d], 16B chunk c stored at c ^ (r&7)          (16 chunks/row)
// VT LDS: [128 d][64 s], 16B chunk c stored at c ^ (d&7)          (8 chunks/row)
// P  LDS: per wave [32 q][72 pad] row-major (scalar writes, b128 reads) — round-1-proven.
__global__ __launch_bounds__(256, 2) void attn_kernel(const __bf16* __restrict__ QKV,
                                                      const __bf16* __restrict__ VT,
                                                      __bf16* __restrict__ AO) {
  __shared__ __bf16 Kl[2][64 * 128];
  __shared__ __bf16 Vt[128 * 64];
  __shared__ __bf16 Pl[4][32 * 72];

  const int tid = threadIdx.x, l = tid & 63, w = tid >> 6;
  const int qt = blockIdx.x, h = blockIdx.y, b = blockIdx.z;
  const int kvh = h >> 2;
  const int g = l >> 4, ln = l & 15;
  const size_t tokQ = (size_t)b * 1024 + qt * 128;
  const __bf16* VTg = VT + ((size_t)(b * 4 + kvh) * 128) * 1024;

  // Q fragments: rows w*32 + mb*16 + ln, k = ks*32 + g*8 + j
  bf16x8 qf[2][4];
  #pragma unroll
  for (int mb = 0; mb < 2; ++mb) {
    const __bf16* qp = QKV + (tokQ + w * 32 + mb * 16 + ln) * 3072 + h * 128;
    #pragma unroll
    for (int ks = 0; ks < 4; ++ks) qf[mb][ks] = *(const bf16x8*)(qp + ks * 32 + g * 8);
  }

  float mrow[2][4], lrow[2][4];
  f32x4 acco[2][8] = {};
  #pragma unroll
  for (int mb = 0; mb < 2; ++mb)
    #pragma unroll
    for (int j = 0; j < 4; ++j) { mrow[mb][j] = -1e30f; lrow[mb][j] = 0.f; }

  auto stageK = [&](int buf, int kt) {
    const __bf16* Kg = QKV + (size_t)(b * 1024 + kt * 64) * 3072 + 2048 + kvh * 128;
    #pragma unroll
    for (int i = 0; i < 4; ++i) {
      int r = i * 16 + (tid >> 4);
      int c = tid & 15;
      int csw = c ^ (r & 7);
      gload_lds16(Kg + (size_t)r * 3072 + csw * 8, (char*)&Kl[buf][0] + i * 4096 + tid * 16);
    }
  };
  auto stageV = [&](int kt) {
    #pragma unroll
    for (int i = 0; i < 4; ++i) {
      int ci = i * 256 + tid;  // 0..1023
      int row = ci >> 3;       // d
      int c = ci & 7;
      int csw = c ^ (row & 7);
      gload_lds16(VTg + (size_t)row * 1024 + kt * 64 + csw * 8, (char*)Vt + (size_t)ci * 16);
    }
  };

  stageK(0, 0);
  const int last = 2 * qt + 1;
  int cur = 0;
  const float scsc = 0.08838834764831845f;  // 1/sqrt(128)

  for (int kt = 0; kt <= last; ++kt) {
    __syncthreads();  // (1) K[cur] staged; prev PV's Vt/Pl reads done

    stageV(kt);                              // single V buffer, lands by barrier (2)
    if (kt + 1 <= last) stageK(cur ^ 1, kt + 1);

    // ---- QK^T ----
    f32x4 accs[2][4] = {};
    #pragma unroll
    for (int cb = 0; cb < 4; ++cb) {
      int n = cb * 16 + ln;
      #pragma unroll
      for (int ks = 0; ks < 4; ++ks) {
        bf16x8 kb = *(const bf16x8*)((const char*)&Kl[cur][0] + n * 256 +
                                     (((ks * 4 + g) ^ (n & 7)) * 16));
        accs[0][cb] = __builtin_amdgcn_mfma_f32_16x16x32_bf16(qf[0][ks], kb, accs[0][cb], 0, 0, 0);
        accs[1][cb] = __builtin_amdgcn_mfma_f32_16x16x32_bf16(qf[1][ks], kb, accs[1][cb], 0, 0, 0);
      }
    }

    // ---- scale + causal mask ----
    const bool diag = (kt >= 2 * qt);
    #pragma unroll
    for (int mb = 0; mb < 2; ++mb)
      #pragma unroll
      for (int cb = 0; cb < 4; ++cb)
        #pragma unroll
        for (int j = 0; j < 4; ++j) {
          float s = accs[mb][cb][j] * scsc;
          if (diag) {
            int row = (int)(qt * 128 + w * 32 + mb * 16 + g * 4 + j);
            int col = kt * 64 + cb * 16 + ln;
            if (col > row) s = -1e30f;
          }
          accs[mb][cb][j] = s;
        }

    // ---- online softmax (row = 16-lane group; 64 cols live across ln in 4 regs) ----
    float mt[2][4];
    #pragma unroll
    for (int mb = 0; mb < 2; ++mb)
      #pragma unroll
      for (int j = 0; j < 4; ++j)
        mt[mb][j] = fmaxf(fmaxf(accs[mb][0][j], accs[mb][1][j]),
                          fmaxf(accs[mb][2][j], accs[mb][3][j]));
    #pragma unroll
    for (int x = 1; x < 16; x <<= 1)
      #pragma unroll
      for (int mb = 0; mb < 2; ++mb)
        #pragma unroll
        for (int j = 0; j < 4; ++j) mt[mb][j] = fmaxf(mt[mb][j], __shfl_xor(mt[mb][j], x, 64));
    float corr[2][4];
    #pragma unroll
    for (int mb = 0; mb < 2; ++mb)
      #pragma unroll
      for (int j = 0; j < 4; ++j) {
        float mnew = fmaxf(mrow[mb][j], mt[mb][j]);
        corr[mb][j] = __expf(mrow[mb][j] - mnew);
        mrow[mb][j] = mnew;
      }
    float rs[2][4] = {};
    #pragma unroll
    for (int mb = 0; mb < 2; ++mb)
      #pragma unroll
      for (int cb = 0; cb < 4; ++cb)
        #pragma unroll
        for (int j = 0; j < 4; ++j) {
          float p = __expf(accs[mb][cb][j] - mrow[mb][j]);
          accs[mb][cb][j] = p;
          rs[mb][j] += p;
        }
    #pragma unroll
    for (int x = 1; x < 16; x <<= 1)
      #pragma unroll
      for (int mb = 0; mb < 2; ++mb)
        #pragma unroll
        for (int j = 0; j < 4; ++j) rs[mb][j] += __shfl_xor(rs[mb][j], x, 64);
    #pragma unroll
    for (int mb = 0; mb < 2; ++mb)
      #pragma unroll
      for (int j = 0; j < 4; ++j) lrow[mb][j] = lrow[mb][j] * corr[mb][j] + rs[mb][j];
    #pragma unroll
    for (int mb = 0; mb < 2; ++mb)
      #pragma unroll
      for (int n = 0; n < 8; ++n)
        #pragma unroll
        for (int j = 0; j < 4; ++j) acco[mb][n][j] *= corr[mb][j];

    // ---- P -> LDS row-major [q][s], scalar u16 (round-1-proven) ----
    {
      __bf16* Pw = &Pl[w][0];
      #pragma unroll
      for (int mb = 0; mb < 2; ++mb)
        #pragma unroll
        for (int cb = 0; cb < 4; ++cb)
          #pragma unroll
          for (int j = 0; j < 4; ++j)
            Pw[(mb * 16 + g * 4 + j) * 72 + cb * 16 + ln] = (__bf16)accs[mb][cb][j];
    }

    __syncthreads();  // (2) Vt staged (vmcnt drained), P visible

    // ---- PV: A = P rows (contig b128), B = VT rows (contig b128, chunk-swizzled) ----
    #pragma unroll
    for (int sc = 0; sc < 2; ++sc) {
      bf16x8 pa[2];
      #pragma unroll
      for (int mb = 0; mb < 2; ++mb)
        pa[mb] = *(const bf16x8*)(&Pl[w][(mb * 16 + ln) * 72 + sc * 32 + g * 8]);
      #pragma unroll
      for (int n = 0; n < 8; ++n) {
        int row = n * 16 + ln;
        bf16x8 vb = *(const bf16x8*)((const char*)Vt + row * 128 +
                                     (((sc * 4 + g) ^ (row & 7)) * 16));
        acco[0][n] = __builtin_amdgcn_mfma_f32_16x16x32_bf16(pa[0], vb, acco[0][n], 0, 0, 0);
        acco[1][n] = __builtin_amdgcn_mfma_f32_16x16x32_bf16(pa[1], vb, acco[1][n], 0, 0, 0);
      }
    }
    cur ^= 1;
  }

  // ---- epilogue ----
  #pragma unroll
  for (int mb = 0; mb < 2; ++mb) {
    float rl[4];
    #pragma unroll
    for (int j = 0; j < 4; ++j) rl[j] = 1.f / lrow[mb][j];
    #pragma unroll
    for (int n = 0; n < 8; ++n)
      #pragma unroll
      for (int j = 0; j < 4; ++j) {
        size_t r = tokQ + w * 32 + mb * 16 + g * 4 + j;
        AO[r * 2048 + h * 128 + n * 16 + ln] = (__bf16)(acco[mb][n][j] * rl[j]);
      }
  }
}

// ---------------- launch ----------------
extern "C" void kernel_launch(void* const* d_in, const int* in_sizes, int n_in,
                              void* d_out, int out_size, void* d_ws, size_t ws_size,
                              hipStream_t stream) {
  const float* x    = (const float*)d_in[0];
  const float* cosb = (const float*)d_in[1];
  const float* sinb = (const float*)d_in[2];
  const float* wq   = (const float*)d_in[3];
  const float* wk   = (const float*)d_in[4];
  const float* wv   = (const float*)d_in[5];
  const float* wo   = (const float*)d_in[6];
  float* out = (float*)d_out;

  char* ws = (char*)d_ws;
  const size_t OFF_XB    = 0;                       // 4096*2048 bf16 = 16 MiB (dead after gemm#1)
  const size_t OFF_WQKVT = OFF_XB + 16777216;       // 3072*2048 bf16 = 12 MiB
  const size_t OFF_WOT   = OFF_WQKVT + 12582912;    // 2048*2048 bf16 = 8 MiB
  const size_t OFF_QKV   = OFF_WOT + 8388608;       // 4096*3072 bf16 = 24 MiB
  const size_t OFF_AO    = OFF_QKV + 25165824;      // 4096*2048 bf16 = 16 MiB
  const size_t OFF_VT    = OFF_XB;                  // 16*128*1024 bf16 = 4 MiB, aliases Xb

  __bf16* Xb    = (__bf16*)(ws + OFF_XB);
  __bf16* WqkvT = (__bf16*)(ws + OFF_WQKVT);
  __bf16* WoT   = (__bf16*)(ws + OFF_WOT);
  __bf16* QKVb  = (__bf16*)(ws + OFF_QKV);
  __bf16* AOb   = (__bf16*)(ws + OFF_AO);
  __bf16* VTb   = (__bf16*)(ws + OFF_VT);

  // 1. convert x
  cvt_kernel<<<4096 * 2048 / 8 / 256, 256, 0, stream>>>(x, Xb, 4096 * 2048);
  // 2. transpose-convert weights
  tcvt_kernel<<<dim3(64, 64), 256, 0, stream>>>(wq, WqkvT, 2048, 2048);
  tcvt_kernel<<<dim3(16, 64), 256, 0, stream>>>(wk, WqkvT + (size_t)2048 * 2048, 2048, 512);
  tcvt_kernel<<<dim3(16, 64), 256, 0, stream>>>(wv, WqkvT + (size_t)2560 * 2048, 2048, 512);
  tcvt_kernel<<<dim3(64, 64), 256, 0, stream>>>(wo, WoT, 2048, 2048);
  // 3. QKV projection (Xb dead after this)
  gemm_bt<__bf16><<<dim3(3072 / BN, 4096 / BM), 256, 0, stream>>>(Xb, WqkvT, QKVb, 4096, 3072, 2048);
  // 4. transpose V into VT (V is not RoPE'd)
  vt_kernel<<<dim3(32, 4, 16), 256, 0, stream>>>(QKVb, VTb);
  // 5. RoPE in place (q + k)
  rope_kernel<<<4096 * 20 * 16 / 256, 256, 0, stream>>>(QKVb, cosb, sinb);
  // 6. attention (Q tile 128, KV tile 64)
  attn_kernel<<<dim3(8, 16, 4), 256, 0, stream>>>(QKVb, VTb, AOb);
  // 7. output projection
  gemm_bt<float><<<dim3(2048 / BN, 4096 / BM), 256, 0, stream>>>(AOb, WoT, out, 4096, 2048, 2048);
}

// Round 5
// 196.199 us; speedup vs baseline: 1.2614x; 1.1736x over previous
//
#include <hip/hip_runtime.h>

typedef __attribute__((ext_vector_type(8))) __bf16 bf16x8;
typedef __attribute__((ext_vector_type(4))) __bf16 bf16x4;
typedef __attribute__((ext_vector_type(4))) float f32x4;

#define DEV static __device__ __forceinline__

DEV void gload_lds16(const void* g, void* l) {
  __builtin_amdgcn_global_load_lds((const __attribute__((address_space(1))) void*)g,
                                   (__attribute__((address_space(3))) void*)l, 16, 0, 0);
}

// ---------------- convert x -> bf16 ----------------
__global__ void cvt_kernel(const float* __restrict__ src, __bf16* __restrict__ dst, int n) {
  int i = (blockIdx.x * 256 + threadIdx.x) * 8;
  if (i >= n) return;
  float4 a = *(const float4*)(src + i);
  float4 b = *(const float4*)(src + i + 4);
  bf16x8 o;
  o[0] = (__bf16)a.x; o[1] = (__bf16)a.y; o[2] = (__bf16)a.z; o[3] = (__bf16)a.w;
  o[4] = (__bf16)b.x; o[5] = (__bf16)b.y; o[6] = (__bf16)b.z; o[7] = (__bf16)b.w;
  *(bf16x8*)(dst + i) = o;
}

// ------------- transpose + convert weights: src K x N (f32) -> dst N x K (bf16) -------------
__global__ void tcvt_kernel(const float* __restrict__ src, __bf16* __restrict__ dst, int K, int N) {
  __shared__ float tile[32][33];
  int k0 = blockIdx.y * 32, n0 = blockIdx.x * 32;
  int tx = threadIdx.x & 31, ty = threadIdx.x >> 5;  // ty 0..7
  #pragma unroll
  for (int i = 0; i < 32; i += 8)
    tile[ty + i][tx] = src[(size_t)(k0 + ty + i) * N + n0 + tx];
  __syncthreads();
  #pragma unroll
  for (int i = 0; i < 32; i += 8)
    dst[(size_t)(n0 + ty + i) * K + k0 + tx] = (__bf16)tile[tx][ty + i];
}

// ------------- transpose V out of QKV: VT[(b*4+kvh)*128 + d][s] = V[b*1024+s][kvh*128+d] -------------
__global__ void vt_kernel(const __bf16* __restrict__ QKV, __bf16* __restrict__ VT) {
  __shared__ __bf16 t[32][33];
  int sx = blockIdx.x;  // 0..31 s-tile within batch
  int dx = blockIdx.y;  // 0..3  d-tile
  int bk = blockIdx.z;  // 0..15 (b*4+kvh)
  int b = bk >> 2, kvh = bk & 3;
  int tx = threadIdx.x & 31, ty = threadIdx.x >> 5;
  #pragma unroll
  for (int i = 0; i < 32; i += 8)
    t[ty + i][tx] = QKV[(size_t)(b * 1024 + sx * 32 + ty + i) * 3072 + 2560 + kvh * 128 + dx * 32 + tx];
  __syncthreads();
  #pragma unroll
  for (int i = 0; i < 32; i += 8)
    VT[((size_t)bk * 128 + dx * 32 + ty + i) * 1024 + sx * 32 + tx] = t[tx][ty + i];
}

// ---------------- GEMM: C[MxN] = A[MxK] @ Bt[NxK]^T, bf16 in, OutT out ----------------
#define BM 128
#define BN 128
#define BKK 32

template <typename OutT>
__global__ __launch_bounds__(256, 2) void gemm_bt(const __bf16* __restrict__ A,
                                                  const __bf16* __restrict__ Bt,
                                                  OutT* __restrict__ C, int M, int N, int K) {
  __shared__ __bf16 As[2][BM * BKK];
  __shared__ __bf16 Bs[2][BM * BKK];
  const int tid = threadIdx.x;
  const int l = tid & 63;
  const int wid = tid >> 6;
  const int wr = wid >> 1, wc = wid & 1;
  const int brow = blockIdx.y * BM, bcol = blockIdx.x * BN;
  const int g = l >> 4, ln = l & 15;

  f32x4 acc[4][4] = {};

  const int NT = K / BKK;

  auto stage = [&](int buf, int kt) {
    #pragma unroll
    for (int i = 0; i < 2; ++i) {
      int row = i * 64 + (tid >> 2);
      int kk = (tid & 3) * 8;
      int kksw = kk ^ (((row >> 1) & 3) * 8);  // source pre-swizzle
      gload_lds16(A + (size_t)(brow + row) * K + kt * BKK + kksw,
                  (char*)&As[buf][0] + i * 4096 + tid * 16);
      gload_lds16(Bt + (size_t)(bcol + row) * K + kt * BKK + kksw,
                  (char*)&Bs[buf][0] + i * 4096 + tid * 16);
    }
  };

  stage(0, 0);
  int cur = 0;
  for (int t = 0; t < NT; ++t) {
    __syncthreads();  // staged buf[cur] ready (drains vmcnt)
    if (t + 1 < NT) stage(cur ^ 1, t + 1);
    bf16x8 af[4], bfr[4];
    #pragma unroll
    for (int m = 0; m < 4; ++m) {
      int row = wr * 64 + m * 16 + ln;
      af[m] = *(const bf16x8*)((const char*)&As[cur][0] + row * 64 +
                               ((g * 8) ^ (((row >> 1) & 3) * 8)) * 2);
    }
    #pragma unroll
    for (int n = 0; n < 4; ++n) {
      int row = wc * 64 + n * 16 + ln;
      bfr[n] = *(const bf16x8*)((const char*)&Bs[cur][0] + row * 64 +
                                ((g * 8) ^ (((row >> 1) & 3) * 8)) * 2);
    }
    #pragma unroll
    for (int m = 0; m < 4; ++m)
      #pragma unroll
      for (int n = 0; n < 4; ++n)
        acc[m][n] = __builtin_amdgcn_mfma_f32_16x16x32_bf16(af[m], bfr[n], acc[m][n], 0, 0, 0);
    cur ^= 1;
  }
  // epilogue: C/D layout col=lane&15, row=(lane>>4)*4+j  [m89-verified]
  #pragma unroll
  for (int m = 0; m < 4; ++m)
    #pragma unroll
    for (int n = 0; n < 4; ++n)
      #pragma unroll
      for (int j = 0; j < 4; ++j) {
        size_t r = brow + wr * 64 + m * 16 + g * 4 + j;
        size_t c = bcol + wc * 64 + n * 16 + ln;
        C[r * N + c] = (OutT)acc[m][n][j];
      }
}

// ---------------- RoPE in place on QKV buffer [4096][3072] ----------------
__global__ void rope_kernel(__bf16* __restrict__ QKV, const float* __restrict__ cosb,
                            const float* __restrict__ sinb) {
  int gid = blockIdx.x * 256 + threadIdx.x;  // total 4096*20*16
  int p = gid & 15;
  int ht = gid >> 4;
  int hc = ht % 20;
  int tok = ht / 20;
  int s = tok & 1023;
  int colb = hc < 16 ? hc * 128 : 2048 + (hc - 16) * 128;
  __bf16* base = QKV + (size_t)tok * 3072 + colb;
  int d0 = p * 4;
  const float* cr = cosb + s * 128;
  const float* sr = sinb + s * 128;
  float x0[4], x1[4];
  #pragma unroll
  for (int j = 0; j < 4; ++j) {
    x0[j] = (float)base[d0 + j];
    x1[j] = (float)base[d0 + 64 + j];
  }
  #pragma unroll
  for (int j = 0; j < 4; ++j) {
    float n0 = x0[j] * cr[d0 + j] - x1[j] * sr[d0 + j];
    float n1 = x1[j] * cr[d0 + 64 + j] + x0[j] * sr[d0 + 64 + j];
    base[d0 + j] = (__bf16)n0;
    base[d0 + 64 + j] = (__bf16)n1;
  }
}

// ---------------- Flash attention (causal, GQA) — transposed orientation ----------------
// QKV [4096][3072] bf16 (q: 0..2047, k: 2048..2559).  VT [16*128][1024] bf16 (pre-transposed V).
// AO  [4096][2048] bf16
// Q tile = 64 rows (4 waves x 16), KV tile = 64. Each block runs two q-tiles: x and 15-x
// (perfect causal load balance: 17 KV-iterations per block).
// S^T = mfma(K, Q): lane holds 16 S-values for ONE q-row (q = ln) -> scalar m/l state,
//   2-shfl row reduction, b64 P-writes.
// O^T = mfma(V^T, P): D-frag q = ln again -> scalar corr; epilogue d-contiguous bf16x4.
// K  LDS: [64 r][128 d], 16B chunk c at c ^ (r&7).
// VT LDS: [128 d][64 s], 16B chunk c at c ^ (d&7).
// P  LDS: per wave [16 q][72 pad] row-major (b64 writes, b128 reads).
__global__ __launch_bounds__(256, 2) void attn_kernel(const __bf16* __restrict__ QKV,
                                                      const __bf16* __restrict__ VT,
                                                      __bf16* __restrict__ AO) {
  __shared__ __bf16 Kl[2][64 * 128];
  __shared__ __bf16 Vt[128 * 64];
  __shared__ __bf16 Pl[4][16 * 72];

  const int tid = threadIdx.x, l = tid & 63, w = tid >> 6;
  const int h = blockIdx.y, b = blockIdx.z;
  const int kvh = h >> 2;
  const int g = l >> 4, ln = l & 15;
  const __bf16* VTg = VT + (size_t)(b * 4 + kvh) * 128 * 1024;
  const float scsc = 0.08838834764831845f;  // 1/sqrt(128)

  auto stageK = [&](int buf, int kt) {
    const __bf16* Kg = QKV + (size_t)(b * 1024 + kt * 64) * 3072 + 2048 + kvh * 128;
    #pragma unroll
    for (int i = 0; i < 4; ++i) {
      int r = i * 16 + (tid >> 4);
      int c = tid & 15;
      int csw = c ^ (r & 7);
      gload_lds16(Kg + (size_t)r * 3072 + csw * 8, (char*)&Kl[buf][0] + i * 4096 + tid * 16);
    }
  };
  auto stageV = [&](int kt) {
    #pragma unroll
    for (int i = 0; i < 4; ++i) {
      int ci = i * 256 + tid;  // 0..1023
      int row = ci >> 3;       // d
      int c = ci & 7;
      int csw = c ^ (row & 7);
      gload_lds16(VTg + (size_t)row * 1024 + kt * 64 + csw * 8, (char*)Vt + (size_t)ci * 16);
    }
  };

  #pragma unroll 1
  for (int pass = 0; pass < 2; ++pass) {
    const int qt = pass ? 15 - (int)blockIdx.x : (int)blockIdx.x;
    const size_t tokQ = (size_t)b * 1024 + qt * 64;

    // Q fragments: B-operand layout — row q = w*16+ln, d = ks*32 + g*8 + j
    bf16x8 qf[4];
    {
      const __bf16* qp = QKV + (tokQ + w * 16 + ln) * 3072 + h * 128;
      #pragma unroll
      for (int ks = 0; ks < 4; ++ks) qf[ks] = *(const bf16x8*)(qp + ks * 32 + g * 8);
    }

    float mrow = -1e30f, lrow = 0.f;
    f32x4 acco[8] = {};

    stageK(0, 0);
    int cur = 0;

    for (int kt = 0; kt <= qt; ++kt) {
      __syncthreads();  // (1) K[cur] staged; prev PV's Vt/Pl reads done

      stageV(kt);                      // single V buffer, lands by barrier (2)
      if (kt < qt) stageK(cur ^ 1, kt + 1);

      // ---- S^T = K · Q^T : accs[cb] lane layout k = cb*16+g*4+j, q = ln ----
      f32x4 accs[4] = {};
      #pragma unroll
      for (int cb = 0; cb < 4; ++cb) {
        int row = cb * 16 + ln;  // k-row of K tile
        #pragma unroll
        for (int ks = 0; ks < 4; ++ks) {
          bf16x8 kb = *(const bf16x8*)((const char*)&Kl[cur][0] + row * 256 +
                                       (((ks * 4 + g) ^ (row & 7)) * 16));
          accs[cb] = __builtin_amdgcn_mfma_f32_16x16x32_bf16(kb, qf[ks], accs[cb], 0, 0, 0);
        }
      }

      // ---- scale + causal mask (tile-local: mask k > q only on diagonal tile) ----
      const bool diag = (kt == qt);
      #pragma unroll
      for (int cb = 0; cb < 4; ++cb)
        #pragma unroll
        for (int j = 0; j < 4; ++j) {
          float s = accs[cb][j] * scsc;
          if (diag && (cb * 16 + g * 4 + j > w * 16 + ln)) s = -1e30f;
          accs[cb][j] = s;
        }

      // ---- online softmax: row lives in this lane (16 vals) + g-replicas ----
      float mt = accs[0][0];
      #pragma unroll
      for (int cb = 0; cb < 4; ++cb)
        #pragma unroll
        for (int j = 0; j < 4; ++j) mt = fmaxf(mt, accs[cb][j]);
      mt = fmaxf(mt, __shfl_xor(mt, 16, 64));
      mt = fmaxf(mt, __shfl_xor(mt, 32, 64));
      float mnew = fmaxf(mrow, mt);
      float corr = __expf(mrow - mnew);
      mrow = mnew;
      float rs = 0.f;
      #pragma unroll
      for (int cb = 0; cb < 4; ++cb)
        #pragma unroll
        for (int j = 0; j < 4; ++j) {
          float p = __expf(accs[cb][j] - mnew);
          accs[cb][j] = p;
          rs += p;
        }
      rs += __shfl_xor(rs, 16, 64);
      rs += __shfl_xor(rs, 32, 64);
      lrow = lrow * corr + rs;
      #pragma unroll
      for (int n = 0; n < 8; ++n)
        #pragma unroll
        for (int j = 0; j < 4; ++j) acco[n][j] *= corr;

      // ---- P -> LDS [q][k] rows: 4 consecutive k per lane => b64 writes ----
      #pragma unroll
      for (int cb = 0; cb < 4; ++cb) {
        bf16x4 pw;
        #pragma unroll
        for (int j = 0; j < 4; ++j) pw[j] = (__bf16)accs[cb][j];
        *(bf16x4*)(&Pl[w][ln * 72 + cb * 16 + g * 4]) = pw;
      }

      __syncthreads();  // (2) Vt staged (vmcnt drained), P visible

      // ---- O^T += V^T · P : A = Vt rows (b128), B = Pl rows (b128) ----
      #pragma unroll
      for (int sc = 0; sc < 2; ++sc) {
        bf16x8 pa = *(const bf16x8*)(&Pl[w][ln * 72 + sc * 32 + g * 8]);
        #pragma unroll
        for (int n = 0; n < 8; ++n) {
          int row = n * 16 + ln;
          bf16x8 vb = *(const bf16x8*)((const char*)Vt + row * 128 +
                                       (((sc * 4 + g) ^ (row & 7)) * 16));
          acco[n] = __builtin_amdgcn_mfma_f32_16x16x32_bf16(vb, pa, acco[n], 0, 0, 0);
        }
      }
      cur ^= 1;
    }

    // ---- epilogue: lane owns q = w*16+ln, d = n*16 + g*4 + j (contiguous 4) ----
    float rl = 1.f / lrow;
    size_t r = tokQ + w * 16 + ln;
    #pragma unroll
    for (int n = 0; n < 8; ++n) {
      bf16x4 ov;
      #pragma unroll
      for (int j = 0; j < 4; ++j) ov[j] = (__bf16)(acco[n][j] * rl);
      *(bf16x4*)(&AO[r * 2048 + h * 128 + n * 16 + g * 4]) = ov;
    }
  }
}

// ---------------- launch ----------------
extern "C" void kernel_launch(void* const* d_in, const int* in_sizes, int n_in,
                              void* d_out, int out_size, void* d_ws, size_t ws_size,
                              hipStream_t stream) {
  const float* x    = (const float*)d_in[0];
  const float* cosb = (const float*)d_in[1];
  const float* sinb = (const float*)d_in[2];
  const float* wq   = (const float*)d_in[3];
  const float* wk   = (const float*)d_in[4];
  const float* wv   = (const float*)d_in[5];
  const float* wo   = (const float*)d_in[6];
  float* out = (float*)d_out;

  char* ws = (char*)d_ws;
  const size_t OFF_XB    = 0;                       // 4096*2048 bf16 = 16 MiB (dead after gemm#1)
  const size_t OFF_WQKVT = OFF_XB + 16777216;       // 3072*2048 bf16 = 12 MiB
  const size_t OFF_WOT   = OFF_WQKVT + 12582912;    // 2048*2048 bf16 = 8 MiB
  const size_t OFF_QKV   = OFF_WOT + 8388608;       // 4096*3072 bf16 = 24 MiB
  const size_t OFF_AO    = OFF_QKV + 25165824;      // 4096*2048 bf16 = 16 MiB
  const size_t OFF_VT    = OFF_XB;                  // 16*128*1024 bf16 = 4 MiB, aliases Xb

  __bf16* Xb    = (__bf16*)(ws + OFF_XB);
  __bf16* WqkvT = (__bf16*)(ws + OFF_WQKVT);
  __bf16* WoT   = (__bf16*)(ws + OFF_WOT);
  __bf16* QKVb  = (__bf16*)(ws + OFF_QKV);
  __bf16* AOb   = (__bf16*)(ws + OFF_AO);
  __bf16* VTb   = (__bf16*)(ws + OFF_VT);

  // 1. convert x
  cvt_kernel<<<4096 * 2048 / 8 / 256, 256, 0, stream>>>(x, Xb, 4096 * 2048);
  // 2. transpose-convert weights
  tcvt_kernel<<<dim3(64, 64), 256, 0, stream>>>(wq, WqkvT, 2048, 2048);
  tcvt_kernel<<<dim3(16, 64), 256, 0, stream>>>(wk, WqkvT + (size_t)2048 * 2048, 2048, 512);
  tcvt_kernel<<<dim3(16, 64), 256, 0, stream>>>(wv, WqkvT + (size_t)2560 * 2048, 2048, 512);
  tcvt_kernel<<<dim3(64, 64), 256, 0, stream>>>(wo, WoT, 2048, 2048);
  // 3. QKV projection (Xb dead after this)
  gemm_bt<__bf16><<<dim3(3072 / BN, 4096 / BM), 256, 0, stream>>>(Xb, WqkvT, QKVb, 4096, 3072, 2048);
  // 4. transpose V into VT (V is not RoPE'd)
  vt_kernel<<<dim3(32, 4, 16), 256, 0, stream>>>(QKVb, VTb);
  // 5. RoPE in place (q + k)
  rope_kernel<<<4096 * 20 * 16 / 256, 256, 0, stream>>>(QKVb, cosb, sinb);
  // 6. attention: Q-tile 64, balanced pairs (x, 15-x)
  attn_kernel<<<dim3(8, 16, 4), 256, 0, stream>>>(QKVb, VTb, AOb);
  // 7. output projection
  gemm_bt<float><<<dim3(2048 / BN, 4096 / BM), 256, 0, stream>>>(AOb, WoT, out, 4096, 2048, 2048);
}

// Round 6
// 193.518 us; speedup vs baseline: 1.2789x; 1.0139x over previous
//
#include <hip/hip_runtime.h>

typedef __attribute__((ext_vector_type(8))) __bf16 bf16x8;
typedef __attribute__((ext_vector_type(4))) __bf16 bf16x4;
typedef __attribute__((ext_vector_type(4))) float f32x4;

#define DEV static __device__ __forceinline__

DEV void gload_lds16(const void* g, void* l) {
  __builtin_amdgcn_global_load_lds((const __attribute__((address_space(1))) void*)g,
                                   (__attribute__((address_space(3))) void*)l, 16, 0, 0);
}

// ---------------- convert x -> bf16 ----------------
__global__ void cvt_kernel(const float* __restrict__ src, __bf16* __restrict__ dst, int n) {
  int i = (blockIdx.x * 256 + threadIdx.x) * 8;
  if (i >= n) return;
  float4 a = *(const float4*)(src + i);
  float4 b = *(const float4*)(src + i + 4);
  bf16x8 o;
  o[0] = (__bf16)a.x; o[1] = (__bf16)a.y; o[2] = (__bf16)a.z; o[3] = (__bf16)a.w;
  o[4] = (__bf16)b.x; o[5] = (__bf16)b.y; o[6] = (__bf16)b.z; o[7] = (__bf16)b.w;
  *(bf16x8*)(dst + i) = o;
}

// ------------- transpose + convert weights: src K x N (f32) -> dst N x K (bf16) -------------
__global__ void tcvt_kernel(const float* __restrict__ src, __bf16* __restrict__ dst, int K, int N) {
  __shared__ float tile[32][33];
  int k0 = blockIdx.y * 32, n0 = blockIdx.x * 32;
  int tx = threadIdx.x & 31, ty = threadIdx.x >> 5;  // ty 0..7
  #pragma unroll
  for (int i = 0; i < 32; i += 8)
    tile[ty + i][tx] = src[(size_t)(k0 + ty + i) * N + n0 + tx];
  __syncthreads();
  #pragma unroll
  for (int i = 0; i < 32; i += 8)
    dst[(size_t)(n0 + ty + i) * K + k0 + tx] = (__bf16)tile[tx][ty + i];
}

// ------------- transpose V out of QKV: VT[(b*4+kvh)*128 + d][s] = V[b*1024+s][kvh*128+d] -------------
__global__ void vt_kernel(const __bf16* __restrict__ QKV, __bf16* __restrict__ VT) {
  __shared__ __bf16 t[32][33];
  int sx = blockIdx.x;  // 0..31 s-tile within batch
  int dx = blockIdx.y;  // 0..3  d-tile
  int bk = blockIdx.z;  // 0..15 (b*4+kvh)
  int b = bk >> 2, kvh = bk & 3;
  int tx = threadIdx.x & 31, ty = threadIdx.x >> 5;
  #pragma unroll
  for (int i = 0; i < 32; i += 8)
    t[ty + i][tx] = QKV[(size_t)(b * 1024 + sx * 32 + ty + i) * 3072 + 2560 + kvh * 128 + dx * 32 + tx];
  __syncthreads();
  #pragma unroll
  for (int i = 0; i < 32; i += 8)
    VT[((size_t)bk * 128 + dx * 32 + ty + i) * 1024 + sx * 32 + tx] = t[tx][ty + i];
}

// ---------------- GEMM: C[MxN] = A[MxK] @ Bt[NxK]^T, bf16 in, OutT out ----------------
#define BM 128
#define BN 128
#define BKK 32

template <typename OutT>
__global__ __launch_bounds__(256, 3) void gemm_bt(const __bf16* __restrict__ A,
                                                  const __bf16* __restrict__ Bt,
                                                  OutT* __restrict__ C, int M, int N, int K) {
  __shared__ __bf16 As[2][BM * BKK];
  __shared__ __bf16 Bs[2][BM * BKK];
  const int tid = threadIdx.x;
  const int l = tid & 63;
  const int wid = tid >> 6;
  const int wr = wid >> 1, wc = wid & 1;

  // XCD-aware bijective block swizzle (grids here are %8 == 0)
  const int nbx = gridDim.x;
  const int nwg = nbx * gridDim.y;
  int lin = blockIdx.y * nbx + blockIdx.x;
  if ((nwg & 7) == 0) lin = (lin & 7) * (nwg >> 3) + (lin >> 3);
  const int brow = (lin / nbx) * BM, bcol = (lin % nbx) * BN;

  const int g = l >> 4, ln = l & 15;

  f32x4 acc[4][4] = {};

  const int NT = K / BKK;

  auto stage = [&](int buf, int kt) {
    #pragma unroll
    for (int i = 0; i < 2; ++i) {
      int row = i * 64 + (tid >> 2);
      int kk = (tid & 3) * 8;
      int kksw = kk ^ (((row >> 1) & 3) * 8);  // source pre-swizzle
      gload_lds16(A + (size_t)(brow + row) * K + kt * BKK + kksw,
                  (char*)&As[buf][0] + i * 4096 + tid * 16);
      gload_lds16(Bt + (size_t)(bcol + row) * K + kt * BKK + kksw,
                  (char*)&Bs[buf][0] + i * 4096 + tid * 16);
    }
  };

  stage(0, 0);
  int cur = 0;
  for (int t = 0; t < NT; ++t) {
    __syncthreads();  // staged buf[cur] ready (drains vmcnt)
    if (t + 1 < NT) stage(cur ^ 1, t + 1);
    bf16x8 af[4], bfr[4];
    #pragma unroll
    for (int m = 0; m < 4; ++m) {
      int row = wr * 64 + m * 16 + ln;
      af[m] = *(const bf16x8*)((const char*)&As[cur][0] + row * 64 +
                               ((g * 8) ^ (((row >> 1) & 3) * 8)) * 2);
    }
    #pragma unroll
    for (int n = 0; n < 4; ++n) {
      int row = wc * 64 + n * 16 + ln;
      bfr[n] = *(const bf16x8*)((const char*)&Bs[cur][0] + row * 64 +
                                ((g * 8) ^ (((row >> 1) & 3) * 8)) * 2);
    }
    __builtin_amdgcn_s_setprio(1);
    #pragma unroll
    for (int m = 0; m < 4; ++m)
      #pragma unroll
      for (int n = 0; n < 4; ++n)
        acc[m][n] = __builtin_amdgcn_mfma_f32_16x16x32_bf16(af[m], bfr[n], acc[m][n], 0, 0, 0);
    __builtin_amdgcn_s_setprio(0);
    cur ^= 1;
  }
  // epilogue: C/D layout col=lane&15, row=(lane>>4)*4+j  [m89-verified]
  #pragma unroll
  for (int m = 0; m < 4; ++m)
    #pragma unroll
    for (int n = 0; n < 4; ++n)
      #pragma unroll
      for (int j = 0; j < 4; ++j) {
        size_t r = brow + wr * 64 + m * 16 + g * 4 + j;
        size_t c = bcol + wc * 64 + n * 16 + ln;
        C[r * N + c] = (OutT)acc[m][n][j];
      }
}

// ---------------- RoPE in place on QKV buffer [4096][3072] ----------------
__global__ void rope_kernel(__bf16* __restrict__ QKV, const float* __restrict__ cosb,
                            const float* __restrict__ sinb) {
  int gid = blockIdx.x * 256 + threadIdx.x;  // total 4096*20*16
  int p = gid & 15;
  int ht = gid >> 4;
  int hc = ht % 20;
  int tok = ht / 20;
  int s = tok & 1023;
  int colb = hc < 16 ? hc * 128 : 2048 + (hc - 16) * 128;
  __bf16* base = QKV + (size_t)tok * 3072 + colb;
  int d0 = p * 4;
  const float* cr = cosb + s * 128;
  const float* sr = sinb + s * 128;
  float x0[4], x1[4];
  #pragma unroll
  for (int j = 0; j < 4; ++j) {
    x0[j] = (float)base[d0 + j];
    x1[j] = (float)base[d0 + 64 + j];
  }
  #pragma unroll
  for (int j = 0; j < 4; ++j) {
    float n0 = x0[j] * cr[d0 + j] - x1[j] * sr[d0 + j];
    float n1 = x1[j] * cr[d0 + 64 + j] + x0[j] * sr[d0 + 64 + j];
    base[d0 + j] = (__bf16)n0;
    base[d0 + 64 + j] = (__bf16)n1;
  }
}

// ---------------- Flash attention (causal, GQA) — transposed orientation ----------------
// QKV [4096][3072] bf16 (q: 0..2047, k: 2048..2559).  VT [16*128][1024] bf16 (pre-transposed V).
// AO  [4096][2048] bf16
// Q tile = 64 rows (4 waves x 16), KV tile = 64. Each block runs two q-tiles: x and 15-x
// (perfect causal load balance: 17 KV-iterations per block).
// S^T = mfma(K, Q): lane holds 16 S-values for ONE q-row (q = ln) -> scalar m/l state,
//   2-shfl row reduction, b64 P-writes.
// O^T = mfma(V^T, P): D-frag q = ln again -> scalar corr; epilogue d-contiguous bf16x4.
__global__ __launch_bounds__(256, 2) void attn_kernel(const __bf16* __restrict__ QKV,
                                                      const __bf16* __restrict__ VT,
                                                      __bf16* __restrict__ AO) {
  __shared__ __bf16 Kl[2][64 * 128];
  __shared__ __bf16 Vt[128 * 64];
  __shared__ __bf16 Pl[4][16 * 72];

  const int tid = threadIdx.x, l = tid & 63, w = tid >> 6;
  const int h = blockIdx.y, b = blockIdx.z;
  const int kvh = h >> 2;
  const int g = l >> 4, ln = l & 15;
  const __bf16* VTg = VT + (size_t)(b * 4 + kvh) * 128 * 1024;
  const float scsc = 0.08838834764831845f;  // 1/sqrt(128)

  auto stageK = [&](int buf, int kt) {
    const __bf16* Kg = QKV + (size_t)(b * 1024 + kt * 64) * 3072 + 2048 + kvh * 128;
    #pragma unroll
    for (int i = 0; i < 4; ++i) {
      int r = i * 16 + (tid >> 4);
      int c = tid & 15;
      int csw = c ^ (r & 7);
      gload_lds16(Kg + (size_t)r * 3072 + csw * 8, (char*)&Kl[buf][0] + i * 4096 + tid * 16);
    }
  };
  auto stageV = [&](int kt) {
    #pragma unroll
    for (int i = 0; i < 4; ++i) {
      int ci = i * 256 + tid;  // 0..1023
      int row = ci >> 3;       // d
      int c = ci & 7;
      int csw = c ^ (row & 7);
      gload_lds16(VTg + (size_t)row * 1024 + kt * 64 + csw * 8, (char*)Vt + (size_t)ci * 16);
    }
  };

  #pragma unroll 1
  for (int pass = 0; pass < 2; ++pass) {
    const int qt = pass ? 15 - (int)blockIdx.x : (int)blockIdx.x;
    const size_t tokQ = (size_t)b * 1024 + qt * 64;

    // Q fragments: B-operand layout — row q = w*16+ln, d = ks*32 + g*8 + j
    bf16x8 qf[4];
    {
      const __bf16* qp = QKV + (tokQ + w * 16 + ln) * 3072 + h * 128;
      #pragma unroll
      for (int ks = 0; ks < 4; ++ks) qf[ks] = *(const bf16x8*)(qp + ks * 32 + g * 8);
    }

    float mrow = -1e30f, lrow = 0.f;
    f32x4 acco[8] = {};

    stageK(0, 0);
    int cur = 0;

    for (int kt = 0; kt <= qt; ++kt) {
      __syncthreads();  // (1) K[cur] staged; prev PV's Vt/Pl reads done

      stageV(kt);                      // single V buffer, lands by barrier (2)
      if (kt < qt) stageK(cur ^ 1, kt + 1);

      // ---- S^T = K · Q^T : accs[cb] lane layout k = cb*16+g*4+j, q = ln ----
      f32x4 accs[4] = {};
      __builtin_amdgcn_s_setprio(1);
      #pragma unroll
      for (int cb = 0; cb < 4; ++cb) {
        int row = cb * 16 + ln;  // k-row of K tile
        #pragma unroll
        for (int ks = 0; ks < 4; ++ks) {
          bf16x8 kb = *(const bf16x8*)((const char*)&Kl[cur][0] + row * 256 +
                                       (((ks * 4 + g) ^ (row & 7)) * 16));
          accs[cb] = __builtin_amdgcn_mfma_f32_16x16x32_bf16(kb, qf[ks], accs[cb], 0, 0, 0);
        }
      }
      __builtin_amdgcn_s_setprio(0);

      // ---- scale + causal mask (tile-local: mask k > q only on diagonal tile) ----
      const bool diag = (kt == qt);
      #pragma unroll
      for (int cb = 0; cb < 4; ++cb)
        #pragma unroll
        for (int j = 0; j < 4; ++j) {
          float s = accs[cb][j] * scsc;
          if (diag && (cb * 16 + g * 4 + j > w * 16 + ln)) s = -1e30f;
          accs[cb][j] = s;
        }

      // ---- online softmax: row lives in this lane (16 vals) + g-replicas ----
      float mt = accs[0][0];
      #pragma unroll
      for (int cb = 0; cb < 4; ++cb)
        #pragma unroll
        for (int j = 0; j < 4; ++j) mt = fmaxf(mt, accs[cb][j]);
      mt = fmaxf(mt, __shfl_xor(mt, 16, 64));
      mt = fmaxf(mt, __shfl_xor(mt, 32, 64));
      float mnew = fmaxf(mrow, mt);
      float corr = __expf(mrow - mnew);
      mrow = mnew;
      float rs = 0.f;
      #pragma unroll
      for (int cb = 0; cb < 4; ++cb)
        #pragma unroll
        for (int j = 0; j < 4; ++j) {
          float p = __expf(accs[cb][j] - mnew);
          accs[cb][j] = p;
          rs += p;
        }
      rs += __shfl_xor(rs, 16, 64);
      rs += __shfl_xor(rs, 32, 64);
      lrow = lrow * corr + rs;
      #pragma unroll
      for (int n = 0; n < 8; ++n)
        #pragma unroll
        for (int j = 0; j < 4; ++j) acco[n][j] *= corr;

      // ---- P -> LDS [q][k] rows: 4 consecutive k per lane => b64 writes ----
      #pragma unroll
      for (int cb = 0; cb < 4; ++cb) {
        bf16x4 pw;
        #pragma unroll
        for (int j = 0; j < 4; ++j) pw[j] = (__bf16)accs[cb][j];
        *(bf16x4*)(&Pl[w][ln * 72 + cb * 16 + g * 4]) = pw;
      }

      __syncthreads();  // (2) Vt staged (vmcnt drained), P visible

      // ---- O^T += V^T · P : A = Vt rows (b128), B = Pl rows (b128) ----
      __builtin_amdgcn_s_setprio(1);
      #pragma unroll
      for (int sc = 0; sc < 2; ++sc) {
        bf16x8 pa = *(const bf16x8*)(&Pl[w][ln * 72 + sc * 32 + g * 8]);
        #pragma unroll
        for (int n = 0; n < 8; ++n) {
          int row = n * 16 + ln;
          bf16x8 vb = *(const bf16x8*)((const char*)Vt + row * 128 +
                                       (((sc * 4 + g) ^ (row & 7)) * 16));
          acco[n] = __builtin_amdgcn_mfma_f32_16x16x32_bf16(vb, pa, acco[n], 0, 0, 0);
        }
      }
      __builtin_amdgcn_s_setprio(0);
      cur ^= 1;
    }

    // ---- epilogue: lane owns q = w*16+ln, d = n*16 + g*4 + j (contiguous 4) ----
    float rl = 1.f / lrow;
    size_t r = tokQ + w * 16 + ln;
    #pragma unroll
    for (int n = 0; n < 8; ++n) {
      bf16x4 ov;
      #pragma unroll
      for (int j = 0; j < 4; ++j) ov[j] = (__bf16)(acco[n][j] * rl);
      *(bf16x4*)(&AO[r * 2048 + h * 128 + n * 16 + g * 4]) = ov;
    }
  }
}

// ---------------- launch ----------------
extern "C" void kernel_launch(void* const* d_in, const int* in_sizes, int n_in,
                              void* d_out, int out_size, void* d_ws, size_t ws_size,
                              hipStream_t stream) {
  const float* x    = (const float*)d_in[0];
  const float* cosb = (const float*)d_in[1];
  const float* sinb = (const float*)d_in[2];
  const float* wq   = (const float*)d_in[3];
  const float* wk   = (const float*)d_in[4];
  const float* wv   = (const float*)d_in[5];
  const float* wo   = (const float*)d_in[6];
  float* out = (float*)d_out;

  char* ws = (char*)d_ws;
  const size_t OFF_XB    = 0;                       // 4096*2048 bf16 = 16 MiB (dead after gemm#1)
  const size_t OFF_WQKVT = OFF_XB + 16777216;       // 3072*2048 bf16 = 12 MiB
  const size_t OFF_WOT   = OFF_WQKVT + 12582912;    // 2048*2048 bf16 = 8 MiB
  const size_t OFF_QKV   = OFF_WOT + 8388608;       // 4096*3072 bf16 = 24 MiB
  const size_t OFF_AO    = OFF_QKV + 25165824;      // 4096*2048 bf16 = 16 MiB
  const size_t OFF_VT    = OFF_XB;                  // 16*128*1024 bf16 = 4 MiB, aliases Xb

  __bf16* Xb    = (__bf16*)(ws + OFF_XB);
  __bf16* WqkvT = (__bf16*)(ws + OFF_WQKVT);
  __bf16* WoT   = (__bf16*)(ws + OFF_WOT);
  __bf16* QKVb  = (__bf16*)(ws + OFF_QKV);
  __bf16* AOb   = (__bf16*)(ws + OFF_AO);
  __bf16* VTb   = (__bf16*)(ws + OFF_VT);

  // 1. convert x
  cvt_kernel<<<4096 * 2048 / 8 / 256, 256, 0, stream>>>(x, Xb, 4096 * 2048);
  // 2. transpose-convert weights
  tcvt_kernel<<<dim3(64, 64), 256, 0, stream>>>(wq, WqkvT, 2048, 2048);
  tcvt_kernel<<<dim3(16, 64), 256, 0, stream>>>(wk, WqkvT + (size_t)2048 * 2048, 2048, 512);
  tcvt_kernel<<<dim3(16, 64), 256, 0, stream>>>(wv, WqkvT + (size_t)2560 * 2048, 2048, 512);
  tcvt_kernel<<<dim3(64, 64), 256, 0, stream>>>(wo, WoT, 2048, 2048);
  // 3. QKV projection (Xb dead after this)
  gemm_bt<__bf16><<<dim3(3072 / BN, 4096 / BM), 256, 0, stream>>>(Xb, WqkvT, QKVb, 4096, 3072, 2048);
  // 4. transpose V into VT (V is not RoPE'd)
  vt_kernel<<<dim3(32, 4, 16), 256, 0, stream>>>(QKVb, VTb);
  // 5. RoPE in place (q + k)
  rope_kernel<<<4096 * 20 * 16 / 256, 256, 0, stream>>>(QKVb, cosb, sinb);
  // 6. attention: Q-tile 64, balanced pairs (x, 15-x)
  attn_kernel<<<dim3(8, 16, 4), 256, 0, stream>>>(QKVb, VTb, AOb);
  // 7. output projection
  gemm_bt<float><<<dim3(2048 / BN, 4096 / BM), 256, 0, stream>>>(AOb, WoT, out, 4096, 2048, 2048);
}

// Round 7
// 192.736 us; speedup vs baseline: 1.2841x; 1.0041x over previous
//
#include <hip/hip_runtime.h>

typedef __attribute__((ext_vector_type(8))) __bf16 bf16x8;
typedef __attribute__((ext_vector_type(4))) __bf16 bf16x4;
typedef __attribute__((ext_vector_type(4))) float f32x4;

#define DEV static __device__ __forceinline__

DEV void gload_lds16(const void* g, void* l) {
  __builtin_amdgcn_global_load_lds((const __attribute__((address_space(1))) void*)g,
                                   (__attribute__((address_space(3))) void*)l, 16, 0, 0);
}

// ---------------- convert x -> bf16 ----------------
__global__ void cvt_kernel(const float* __restrict__ src, __bf16* __restrict__ dst, int n) {
  int i = (blockIdx.x * 256 + threadIdx.x) * 8;
  if (i >= n) return;
  float4 a = *(const float4*)(src + i);
  float4 b = *(const float4*)(src + i + 4);
  bf16x8 o;
  o[0] = (__bf16)a.x; o[1] = (__bf16)a.y; o[2] = (__bf16)a.z; o[3] = (__bf16)a.w;
  o[4] = (__bf16)b.x; o[5] = (__bf16)b.y; o[6] = (__bf16)b.z; o[7] = (__bf16)b.w;
  *(bf16x8*)(dst + i) = o;
}

// ------------- transpose + convert weights: src K x N (f32) -> dst N x K (bf16) -------------
__global__ void tcvt_kernel(const float* __restrict__ src, __bf16* __restrict__ dst, int K, int N) {
  __shared__ float tile[32][33];
  int k0 = blockIdx.y * 32, n0 = blockIdx.x * 32;
  int tx = threadIdx.x & 31, ty = threadIdx.x >> 5;  // ty 0..7
  #pragma unroll
  for (int i = 0; i < 32; i += 8)
    tile[ty + i][tx] = src[(size_t)(k0 + ty + i) * N + n0 + tx];
  __syncthreads();
  #pragma unroll
  for (int i = 0; i < 32; i += 8)
    dst[(size_t)(n0 + ty + i) * K + k0 + tx] = (__bf16)tile[tx][ty + i];
}

// ------------- transpose V out of QKV: VT[(b*4+kvh)*128 + d][s] = V[b*1024+s][kvh*128+d] -------------
__global__ void vt_kernel(const __bf16* __restrict__ QKV, __bf16* __restrict__ VT) {
  __shared__ __bf16 t[32][33];
  int sx = blockIdx.x;  // 0..31 s-tile within batch
  int dx = blockIdx.y;  // 0..3  d-tile
  int bk = blockIdx.z;  // 0..15 (b*4+kvh)
  int b = bk >> 2, kvh = bk & 3;
  int tx = threadIdx.x & 31, ty = threadIdx.x >> 5;
  #pragma unroll
  for (int i = 0; i < 32; i += 8)
    t[ty + i][tx] = QKV[(size_t)(b * 1024 + sx * 32 + ty + i) * 3072 + 2560 + kvh * 128 + dx * 32 + tx];
  __syncthreads();
  #pragma unroll
  for (int i = 0; i < 32; i += 8)
    VT[((size_t)bk * 128 + dx * 32 + ty + i) * 1024 + sx * 32 + tx] = t[tx][ty + i];
}

// ---------------- GEMM: C[MxN] = A[MxK] @ Bt[NxK]^T, bf16 in, OutT out ----------------
// 2-tile-deep pipeline with raw s_barrier + COUNTED vmcnt (no vmcnt(0) drain in
// steady state — T4). stage(t), stage(t+1) up front; iter t: wait vmcnt(4)
// (tile t landed, t+1 in flight), barrier, ds_read+MFMA, barrier, stage t+2
// into the freed buffer.
#define BM 128
#define BN 128
#define BKK 32

template <typename OutT>
__global__ __launch_bounds__(256, 4) void gemm_bt(const __bf16* __restrict__ A,
                                                  const __bf16* __restrict__ Bt,
                                                  OutT* __restrict__ C, int M, int N, int K) {
  __shared__ __bf16 As[2][BM * BKK];
  __shared__ __bf16 Bs[2][BM * BKK];
  const int tid = threadIdx.x;
  const int l = tid & 63;
  const int wid = tid >> 6;
  const int wr = wid >> 1, wc = wid & 1;

  // XCD-aware bijective block swizzle (grids here are %8 == 0)
  const int nbx = gridDim.x;
  const int nwg = nbx * gridDim.y;
  int lin = blockIdx.y * nbx + blockIdx.x;
  if ((nwg & 7) == 0) lin = (lin & 7) * (nwg >> 3) + (lin >> 3);
  const int brow = (lin / nbx) * BM, bcol = (lin % nbx) * BN;

  const int g = l >> 4, ln = l & 15;

  f32x4 acc[4][4] = {};

  const int NT = K / BKK;

  auto stage = [&](int buf, int kt) {  // 4 gload_lds per thread
    #pragma unroll
    for (int i = 0; i < 2; ++i) {
      int row = i * 64 + (tid >> 2);
      int kk = (tid & 3) * 8;
      int kksw = kk ^ (((row >> 1) & 3) * 8);  // source pre-swizzle
      gload_lds16(A + (size_t)(brow + row) * K + kt * BKK + kksw,
                  (char*)&As[buf][0] + i * 4096 + tid * 16);
      gload_lds16(Bt + (size_t)(bcol + row) * K + kt * BKK + kksw,
                  (char*)&Bs[buf][0] + i * 4096 + tid * 16);
    }
  };

  stage(0, 0);
  stage(1, 1);
  int cur = 0;
  for (int t = 0; t < NT; ++t) {
    // wait own tile-t loads: t+1's 4 loads may stay in flight
    if (t + 1 < NT) {
      asm volatile("s_waitcnt vmcnt(4)" ::: "memory");
    } else {
      asm volatile("s_waitcnt vmcnt(0)" ::: "memory");
    }
    __builtin_amdgcn_sched_barrier(0);
    __builtin_amdgcn_s_barrier();  // all waves: tile t resident
    __builtin_amdgcn_sched_barrier(0);

    bf16x8 af[4], bfr[4];
    #pragma unroll
    for (int m = 0; m < 4; ++m) {
      int row = wr * 64 + m * 16 + ln;
      af[m] = *(const bf16x8*)((const char*)&As[cur][0] + row * 64 +
                               ((g * 8) ^ (((row >> 1) & 3) * 8)) * 2);
    }
    #pragma unroll
    for (int n = 0; n < 4; ++n) {
      int row = wc * 64 + n * 16 + ln;
      bfr[n] = *(const bf16x8*)((const char*)&Bs[cur][0] + row * 64 +
                                ((g * 8) ^ (((row >> 1) & 3) * 8)) * 2);
    }
    __builtin_amdgcn_s_setprio(1);
    #pragma unroll
    for (int m = 0; m < 4; ++m)
      #pragma unroll
      for (int n = 0; n < 4; ++n)
        acc[m][n] = __builtin_amdgcn_mfma_f32_16x16x32_bf16(af[m], bfr[n], acc[m][n], 0, 0, 0);
    __builtin_amdgcn_s_setprio(0);

    __builtin_amdgcn_sched_barrier(0);
    __builtin_amdgcn_s_barrier();  // all waves done reading buf[cur]
    __builtin_amdgcn_sched_barrier(0);
    if (t + 2 < NT) stage(cur, t + 2);  // overwrite freed buffer
    cur ^= 1;
  }
  // epilogue: C/D layout col=lane&15, row=(lane>>4)*4+j  [m89-verified]
  #pragma unroll
  for (int m = 0; m < 4; ++m)
    #pragma unroll
    for (int n = 0; n < 4; ++n)
      #pragma unroll
      for (int j = 0; j < 4; ++j) {
        size_t r = brow + wr * 64 + m * 16 + g * 4 + j;
        size_t c = bcol + wc * 64 + n * 16 + ln;
        C[r * N + c] = (OutT)acc[m][n][j];
      }
}

// ---------------- RoPE in place on QKV buffer [4096][3072] ----------------
__global__ void rope_kernel(__bf16* __restrict__ QKV, const float* __restrict__ cosb,
                            const float* __restrict__ sinb) {
  int gid = blockIdx.x * 256 + threadIdx.x;  // total 4096*20*16
  int p = gid & 15;
  int ht = gid >> 4;
  int hc = ht % 20;
  int tok = ht / 20;
  int s = tok & 1023;
  int colb = hc < 16 ? hc * 128 : 2048 + (hc - 16) * 128;
  __bf16* base = QKV + (size_t)tok * 3072 + colb;
  int d0 = p * 4;
  const float* cr = cosb + s * 128;
  const float* sr = sinb + s * 128;
  float x0[4], x1[4];
  #pragma unroll
  for (int j = 0; j < 4; ++j) {
    x0[j] = (float)base[d0 + j];
    x1[j] = (float)base[d0 + 64 + j];
  }
  #pragma unroll
  for (int j = 0; j < 4; ++j) {
    float n0 = x0[j] * cr[d0 + j] - x1[j] * sr[d0 + j];
    float n1 = x1[j] * cr[d0 + 64 + j] + x0[j] * sr[d0 + 64 + j];
    base[d0 + j] = (__bf16)n0;
    base[d0 + 64 + j] = (__bf16)n1;
  }
}

// ---------------- Flash attention (causal, GQA) — transposed orientation ----------------
// QKV [4096][3072] bf16 (q: 0..2047, k: 2048..2559).  VT [16*128][1024] bf16 (pre-transposed V).
// AO  [4096][2048] bf16
// Q tile = 64 rows (4 waves x 16), KV tile = 64. Each block runs two q-tiles: x and 15-x
// (perfect causal load balance: 17 KV-iterations per block).
// S^T = mfma(K, Q): lane holds 16 S-values for ONE q-row (q = ln) -> scalar m/l state,
//   2-shfl row reduction, b64 P-writes.
// O^T = mfma(V^T, P): D-frag q = ln again -> scalar corr; epilogue d-contiguous bf16x4.
__global__ __launch_bounds__(256, 2) void attn_kernel(const __bf16* __restrict__ QKV,
                                                      const __bf16* __restrict__ VT,
                                                      __bf16* __restrict__ AO) {
  __shared__ __bf16 Kl[2][64 * 128];
  __shared__ __bf16 Vt[128 * 64];
  __shared__ __bf16 Pl[4][16 * 72];

  const int tid = threadIdx.x, l = tid & 63, w = tid >> 6;
  const int h = blockIdx.y, b = blockIdx.z;
  const int kvh = h >> 2;
  const int g = l >> 4, ln = l & 15;
  const __bf16* VTg = VT + (size_t)(b * 4 + kvh) * 128 * 1024;
  const float scsc = 0.08838834764831845f;  // 1/sqrt(128)

  auto stageK = [&](int buf, int kt) {
    const __bf16* Kg = QKV + (size_t)(b * 1024 + kt * 64) * 3072 + 2048 + kvh * 128;
    #pragma unroll
    for (int i = 0; i < 4; ++i) {
      int r = i * 16 + (tid >> 4);
      int c = tid & 15;
      int csw = c ^ (r & 7);
      gload_lds16(Kg + (size_t)r * 3072 + csw * 8, (char*)&Kl[buf][0] + i * 4096 + tid * 16);
    }
  };
  auto stageV = [&](int kt) {
    #pragma unroll
    for (int i = 0; i < 4; ++i) {
      int ci = i * 256 + tid;  // 0..1023
      int row = ci >> 3;       // d
      int c = ci & 7;
      int csw = c ^ (row & 7);
      gload_lds16(VTg + (size_t)row * 1024 + kt * 64 + csw * 8, (char*)Vt + (size_t)ci * 16);
    }
  };

  #pragma unroll 1
  for (int pass = 0; pass < 2; ++pass) {
    const int qt = pass ? 15 - (int)blockIdx.x : (int)blockIdx.x;
    const size_t tokQ = (size_t)b * 1024 + qt * 64;

    // Q fragments: B-operand layout — row q = w*16+ln, d = ks*32 + g*8 + j
    bf16x8 qf[4];
    {
      const __bf16* qp = QKV + (tokQ + w * 16 + ln) * 3072 + h * 128;
      #pragma unroll
      for (int ks = 0; ks < 4; ++ks) qf[ks] = *(const bf16x8*)(qp + ks * 32 + g * 8);
    }

    float mrow = -1e30f, lrow = 0.f;
    f32x4 acco[8] = {};

    stageK(0, 0);
    int cur = 0;

    for (int kt = 0; kt <= qt; ++kt) {
      __syncthreads();  // (1) K[cur] staged; prev PV's Vt/Pl reads done

      stageV(kt);                      // single V buffer, lands by barrier (2)
      if (kt < qt) stageK(cur ^ 1, kt + 1);

      // ---- S^T = K · Q^T : accs[cb] lane layout k = cb*16+g*4+j, q = ln ----
      f32x4 accs[4] = {};
      __builtin_amdgcn_s_setprio(1);
      #pragma unroll
      for (int cb = 0; cb < 4; ++cb) {
        int row = cb * 16 + ln;  // k-row of K tile
        #pragma unroll
        for (int ks = 0; ks < 4; ++ks) {
          bf16x8 kb = *(const bf16x8*)((const char*)&Kl[cur][0] + row * 256 +
                                       (((ks * 4 + g) ^ (row & 7)) * 16));
          accs[cb] = __builtin_amdgcn_mfma_f32_16x16x32_bf16(kb, qf[ks], accs[cb], 0, 0, 0);
        }
      }
      __builtin_amdgcn_s_setprio(0);

      // ---- scale + causal mask (tile-local: mask k > q only on diagonal tile) ----
      const bool diag = (kt == qt);
      #pragma unroll
      for (int cb = 0; cb < 4; ++cb)
        #pragma unroll
        for (int j = 0; j < 4; ++j) {
          float s = accs[cb][j] * scsc;
          if (diag && (cb * 16 + g * 4 + j > w * 16 + ln)) s = -1e30f;
          accs[cb][j] = s;
        }

      // ---- online softmax: row lives in this lane (16 vals) + g-replicas ----
      float mt = accs[0][0];
      #pragma unroll
      for (int cb = 0; cb < 4; ++cb)
        #pragma unroll
        for (int j = 0; j < 4; ++j) mt = fmaxf(mt, accs[cb][j]);
      mt = fmaxf(mt, __shfl_xor(mt, 16, 64));
      mt = fmaxf(mt, __shfl_xor(mt, 32, 64));
      float mnew = fmaxf(mrow, mt);
      float corr = __expf(mrow - mnew);
      mrow = mnew;
      float rs = 0.f;
      #pragma unroll
      for (int cb = 0; cb < 4; ++cb)
        #pragma unroll
        for (int j = 0; j < 4; ++j) {
          float p = __expf(accs[cb][j] - mnew);
          accs[cb][j] = p;
          rs += p;
        }
      rs += __shfl_xor(rs, 16, 64);
      rs += __shfl_xor(rs, 32, 64);
      lrow = lrow * corr + rs;
      #pragma unroll
      for (int n = 0; n < 8; ++n)
        #pragma unroll
        for (int j = 0; j < 4; ++j) acco[n][j] *= corr;

      // ---- P -> LDS [q][k] rows: 4 consecutive k per lane => b64 writes ----
      #pragma unroll
      for (int cb = 0; cb < 4; ++cb) {
        bf16x4 pw;
        #pragma unroll
        for (int j = 0; j < 4; ++j) pw[j] = (__bf16)accs[cb][j];
        *(bf16x4*)(&Pl[w][ln * 72 + cb * 16 + g * 4]) = pw;
      }

      __syncthreads();  // (2) Vt staged (vmcnt drained), P visible

      // ---- O^T += V^T · P : A = Vt rows (b128), B = Pl rows (b128) ----
      __builtin_amdgcn_s_setprio(1);
      #pragma unroll
      for (int sc = 0; sc < 2; ++sc) {
        bf16x8 pa = *(const bf16x8*)(&Pl[w][ln * 72 + sc * 32 + g * 8]);
        #pragma unroll
        for (int n = 0; n < 8; ++n) {
          int row = n * 16 + ln;
          bf16x8 vb = *(const bf16x8*)((const char*)Vt + row * 128 +
                                       (((sc * 4 + g) ^ (row & 7)) * 16));
          acco[n] = __builtin_amdgcn_mfma_f32_16x16x32_bf16(vb, pa, acco[n], 0, 0, 0);
        }
      }
      __builtin_amdgcn_s_setprio(0);
      cur ^= 1;
    }

    // ---- epilogue: lane owns q = w*16+ln, d = n*16 + g*4 + j (contiguous 4) ----
    float rl = 1.f / lrow;
    size_t r = tokQ + w * 16 + ln;
    #pragma unroll
    for (int n = 0; n < 8; ++n) {
      bf16x4 ov;
      #pragma unroll
      for (int j = 0; j < 4; ++j) ov[j] = (__bf16)(acco[n][j] * rl);
      *(bf16x4*)(&AO[r * 2048 + h * 128 + n * 16 + g * 4]) = ov;
    }
  }
}

// ---------------- launch ----------------
extern "C" void kernel_launch(void* const* d_in, const int* in_sizes, int n_in,
                              void* d_out, int out_size, void* d_ws, size_t ws_size,
                              hipStream_t stream) {
  const float* x    = (const float*)d_in[0];
  const float* cosb = (const float*)d_in[1];
  const float* sinb = (const float*)d_in[2];
  const float* wq   = (const float*)d_in[3];
  const float* wk   = (const float*)d_in[4];
  const float* wv   = (const float*)d_in[5];
  const float* wo   = (const float*)d_in[6];
  float* out = (float*)d_out;

  char* ws = (char*)d_ws;
  const size_t OFF_XB    = 0;                       // 4096*2048 bf16 = 16 MiB (dead after gemm#1)
  const size_t OFF_WQKVT = OFF_XB + 16777216;       // 3072*2048 bf16 = 12 MiB
  const size_t OFF_WOT   = OFF_WQKVT + 12582912;    // 2048*2048 bf16 = 8 MiB
  const size_t OFF_QKV   = OFF_WOT + 8388608;       // 4096*3072 bf16 = 24 MiB
  const size_t OFF_AO    = OFF_QKV + 25165824;      // 4096*2048 bf16 = 16 MiB
  const size_t OFF_VT    = OFF_XB;                  // 16*128*1024 bf16 = 4 MiB, aliases Xb

  __bf16* Xb    = (__bf16*)(ws + OFF_XB);
  __bf16* WqkvT = (__bf16*)(ws + OFF_WQKVT);
  __bf16* WoT   = (__bf16*)(ws + OFF_WOT);
  __bf16* QKVb  = (__bf16*)(ws + OFF_QKV);
  __bf16* AOb   = (__bf16*)(ws + OFF_AO);
  __bf16* VTb   = (__bf16*)(ws + OFF_VT);

  // 1. convert x
  cvt_kernel<<<4096 * 2048 / 8 / 256, 256, 0, stream>>>(x, Xb, 4096 * 2048);
  // 2. transpose-convert weights
  tcvt_kernel<<<dim3(64, 64), 256, 0, stream>>>(wq, WqkvT, 2048, 2048);
  tcvt_kernel<<<dim3(16, 64), 256, 0, stream>>>(wk, WqkvT + (size_t)2048 * 2048, 2048, 512);
  tcvt_kernel<<<dim3(16, 64), 256, 0, stream>>>(wv, WqkvT + (size_t)2560 * 2048, 2048, 512);
  tcvt_kernel<<<dim3(64, 64), 256, 0, stream>>>(wo, WoT, 2048, 2048);
  // 3. QKV projection (Xb dead after this)
  gemm_bt<__bf16><<<dim3(3072 / BN, 4096 / BM), 256, 0, stream>>>(Xb, WqkvT, QKVb, 4096, 3072, 2048);
  // 4. transpose V into VT (V is not RoPE'd)
  vt_kernel<<<dim3(32, 4, 16), 256, 0, stream>>>(QKVb, VTb);
  // 5. RoPE in place (q + k)
  rope_kernel<<<4096 * 20 * 16 / 256, 256, 0, stream>>>(QKVb, cosb, sinb);
  // 6. attention: Q-tile 64, balanced pairs (x, 15-x)
  attn_kernel<<<dim3(8, 16, 4), 256, 0, stream>>>(QKVb, VTb, AOb);
  // 7. output projection
  gemm_bt<float><<<dim3(2048 / BN, 4096 / BM), 256, 0, stream>>>(AOb, WoT, out, 4096, 2048, 2048);
}

// Round 9
// 175.285 us; speedup vs baseline: 1.4119x; 1.0996x over previous
//
#include <hip/hip_runtime.h>

typedef __attribute__((ext_vector_type(8))) __bf16 bf16x8;
typedef __attribute__((ext_vector_type(4))) __bf16 bf16x4;
typedef __attribute__((ext_vector_type(4))) float f32x4;

#define DEV static __device__ __forceinline__

DEV void gload_lds16(const void* g, void* l) {
  __builtin_amdgcn_global_load_lds((const __attribute__((address_space(1))) void*)g,
                                   (__attribute__((address_space(3))) void*)l, 16, 0, 0);
}

DEV void lgkm0_sb() {
  asm volatile("s_waitcnt lgkmcnt(0)" ::: "memory");
  __builtin_amdgcn_sched_barrier(0);
}

// ---------------- convert x -> bf16 ----------------
__global__ void cvt_kernel(const float* __restrict__ src, __bf16* __restrict__ dst, int n) {
  int i = (blockIdx.x * 256 + threadIdx.x) * 8;
  if (i >= n) return;
  float4 a = *(const float4*)(src + i);
  float4 b = *(const float4*)(src + i + 4);
  bf16x8 o;
  o[0] = (__bf16)a.x; o[1] = (__bf16)a.y; o[2] = (__bf16)a.z; o[3] = (__bf16)a.w;
  o[4] = (__bf16)b.x; o[5] = (__bf16)b.y; o[6] = (__bf16)b.z; o[7] = (__bf16)b.w;
  *(bf16x8*)(dst + i) = o;
}

// ------------- transpose + convert weights: src K x N (f32) -> dst N x K (bf16) -------------
__global__ void tcvt_kernel(const float* __restrict__ src, __bf16* __restrict__ dst, int K, int N) {
  __shared__ float tile[32][33];
  int k0 = blockIdx.y * 32, n0 = blockIdx.x * 32;
  int tx = threadIdx.x & 31, ty = threadIdx.x >> 5;  // ty 0..7
  #pragma unroll
  for (int i = 0; i < 32; i += 8)
    tile[ty + i][tx] = src[(size_t)(k0 + ty + i) * N + n0 + tx];
  __syncthreads();
  #pragma unroll
  for (int i = 0; i < 32; i += 8)
    dst[(size_t)(n0 + ty + i) * K + k0 + tx] = (__bf16)tile[tx][ty + i];
}

// ------------- transpose V out of QKV: VT[(b*4+kvh)*128 + d][s] = V[b*1024+s][kvh*128+d] -------------
__global__ void vt_kernel(const __bf16* __restrict__ QKV, __bf16* __restrict__ VT) {
  __shared__ __bf16 t[32][33];
  int sx = blockIdx.x;  // 0..31 s-tile within batch
  int dx = blockIdx.y;  // 0..3  d-tile
  int bk = blockIdx.z;  // 0..15 (b*4+kvh)
  int b = bk >> 2, kvh = bk & 3;
  int tx = threadIdx.x & 31, ty = threadIdx.x >> 5;
  #pragma unroll
  for (int i = 0; i < 32; i += 8)
    t[ty + i][tx] = QKV[(size_t)(b * 1024 + sx * 32 + ty + i) * 3072 + 2560 + kvh * 128 + dx * 32 + tx];
  __syncthreads();
  #pragma unroll
  for (int i = 0; i < 32; i += 8)
    VT[((size_t)bk * 128 + dx * 32 + ty + i) * 1024 + sx * 32 + tx] = t[tx][ty + i];
}

// ================= 8-phase GEMM: C[MxN] = A[MxK] @ Bt[NxK]^T =================
// BN=256, BK=64, 512 thr = 8 waves (2M x 4N). K=2048 -> NT=32 K-tiles.
// LDS: 2 bufs x (A BM*64 + B 256*64) bf16, subtiled [16 r][32 c] with st_16x32
// XOR swizzle (byte ^= ((row&8)?32:0)), staged via inverse-swizzled global src.
// Phase structure (race-fixed vs R8): reads at TOP of phase consume data
// guaranteed by the PREVIOUS phase's {vmcnt wait -> barrier} pair; the counted
// vmcnt for the NEXT phase's reads sits AFTER this phase's MFMA, BEFORE its end
// barrier — every wave's own-wait precedes the common barrier (R7-proven order).
// Waits (BM=256): end-p0 vmcnt(10), end-p1 vmcnt(12), end-p2 none, end-p3
// vmcnt(12), prologue vmcnt(12).  (BM=128): 7 / 9 / none / 9, prologue 9.
template <int BM, typename OutT>
__global__ __launch_bounds__(512, 2) void gemm8p(const __bf16* __restrict__ A,
                                                 const __bf16* __restrict__ Bt,
                                                 OutT* __restrict__ C,
                                                 int M, int N, int K) {
  constexpr int ABYTES = BM * 64 * 2;
  constexpr int BBYTES = 256 * 64 * 2;
  constexpr int MH = BM / 64;  // m-frags per half per wave (256->4, 128->2)
  __shared__ alignas(1024) char smem[2 * (ABYTES + BBYTES)];

  const int tid = threadIdx.x;
  const int l = tid & 63, w = tid >> 6;
  const int wr = w >> 2, wc = w & 3;
  const int g = l >> 4, ln = l & 15;

  const int nbx = gridDim.x;
  const int nwg = nbx * gridDim.y;
  int lin = blockIdx.y * nbx + blockIdx.x;
  lin = (lin & 7) * (nwg >> 3) + (lin >> 3);  // bijective: nwg % 8 == 0
  const int brow = (lin / nbx) * BM, bcol = (lin % nbx) * 256;

  const __bf16* Ag = A + (size_t)brow * K;
  const __bf16* Bg = Bt + (size_t)bcol * K;
  const int NT = K / 64;

  auto Abuf = [&](int buf) -> char* { return smem + buf * ABYTES; };
  auto Bbuf = [&](int buf) -> char* { return smem + 2 * ABYTES + buf * BBYTES; };

  f32x4 acc[2 * MH][4] = {};

  // one 16B chunk: LDS linear (sub,lane) <- global (inverse-swizzled source)
  auto chunk = [&](const __bf16* gb, char* lb, int ktc, int sub) {
    int r16 = l >> 2;
    int colb = ((l & 3) * 16) ^ (((l >> 5) & 1) << 5);  // (r16>>3)&1 == (l>>5)&1
    int row = (sub >> 1) * 16 + r16;
    gload_lds16(gb + (size_t)row * K + ktc * 64 + (sub & 1) * 32 + (colb >> 1),
                lb + sub * 1024 + l * 16);
  };
  auto stA0 = [&](int ktc, int buf) {  // A m-half0 regions
    if constexpr (BM == 256) {
      #pragma unroll
      for (int i = 0; i < 2; ++i) { int idx = i * 8 + w; chunk(Ag, Abuf(buf), ktc, (idx >> 3) * 16 + (idx & 7)); }
    } else {
      chunk(Ag, Abuf(buf), ktc, (w >> 2) * 8 + (w & 3));
    }
  };
  auto stA1 = [&](int ktc, int buf) {  // A m-half1
    if constexpr (BM == 256) {
      #pragma unroll
      for (int i = 0; i < 2; ++i) { int idx = i * 8 + w; chunk(Ag, Abuf(buf), ktc, 8 + (idx >> 3) * 16 + (idx & 7)); }
    } else {
      chunk(Ag, Abuf(buf), ktc, 4 + (w >> 2) * 8 + (w & 3));
    }
  };
  auto stB0 = [&](int ktc, int buf) {  // B n01
    #pragma unroll
    for (int i = 0; i < 2; ++i) { int idx = i * 8 + w; chunk(Bg, Bbuf(buf), ktc, (idx >> 2) * 8 + (idx & 3)); }
  };
  auto stB1 = [&](int ktc, int buf) {  // B n23
    #pragma unroll
    for (int i = 0; i < 2; ++i) { int idx = i * 8 + w; chunk(Bg, Bbuf(buf), ktc, 4 + (idx >> 2) * 8 + (idx & 3)); }
  };

  // fragment reads (forward swizzle)
  auto ldA = [&](int buf, int m, int kk) -> bf16x8 {
    int sub = (wr * (BM / 32) + m) * 2 + kk;
    return *(const bf16x8*)(Abuf(buf) + sub * 1024 + ln * 64 + ((g * 16) ^ (((ln >> 3) & 1) << 5)));
  };
  auto ldB = [&](int buf, int n, int kk) -> bf16x8 {
    int sub = (wc * 4 + n) * 2 + kk;
    return *(const bf16x8*)(Bbuf(buf) + sub * 1024 + ln * 64 + ((g * 16) ^ (((ln >> 3) & 1) << 5)));
  };

  auto vmw = [&](int which) {  // counted waits; each precedes a barrier
    if constexpr (BM == 256) {
      if (which == 0) asm volatile("s_waitcnt vmcnt(10)" ::: "memory");
      else if (which == 1) asm volatile("s_waitcnt vmcnt(12)" ::: "memory");
      else asm volatile("s_waitcnt vmcnt(12)" ::: "memory");
    } else {
      if (which == 0) asm volatile("s_waitcnt vmcnt(7)" ::: "memory");
      else if (which == 1) asm volatile("s_waitcnt vmcnt(9)" ::: "memory");
      else asm volatile("s_waitcnt vmcnt(9)" ::: "memory");
    }
    __builtin_amdgcn_sched_barrier(0);
  };
  auto bar = [&]() {
    __builtin_amdgcn_sched_barrier(0);
    __builtin_amdgcn_s_barrier();
    __builtin_amdgcn_sched_barrier(0);
  };

  // prologue: K-tiles 0,1 staged; wait so that A0/B01 of tile 0 are resident,
  // then barrier (all waves' waits precede it) before first reads.
  stA0(0, 0); stB0(0, 0); stB1(0, 0); stA1(0, 0);
  stA0(1, 1); stB0(1, 1); stB1(1, 1); stA1(1, 1);
  vmw(2);  // 12 (BM=256) / 9 (BM=128)
  bar();

  bf16x8 af[MH][2], bf[4][2];

  for (int kt = 0; kt < NT; ++kt) {
    const int buf = kt & 1;
    const int ktc = (kt + 2) & 31;  // always-stage (wrap tiles never read)

    // ---- phase 0: read A-half0 + B-n01 (guaranteed); MFMA half0 x n01; wait for B-n23 ----
    #pragma unroll
    for (int m = 0; m < MH; ++m) { af[m][0] = ldA(buf, m, 0); af[m][1] = ldA(buf, m, 1); }
    #pragma unroll
    for (int n = 0; n < 2; ++n) { bf[n][0] = ldB(buf, n, 0); bf[n][1] = ldB(buf, n, 1); }
    bar();
    lgkm0_sb();
    __builtin_amdgcn_s_setprio(1);
    #pragma unroll
    for (int m = 0; m < MH; ++m)
      #pragma unroll
      for (int n = 0; n < 2; ++n)
        #pragma unroll
        for (int kk = 0; kk < 2; ++kk)
          acc[m][n] = __builtin_amdgcn_mfma_f32_16x16x32_bf16(af[m][kk], bf[n][kk], acc[m][n], 0, 0, 0);
    __builtin_amdgcn_s_setprio(0);
    vmw(0);
    bar();

    // ---- phase 1: read B-n23; stage A-half0+B-n01 of kt+2; MFMA half0 x n23; wait for A-half1 ----
    #pragma unroll
    for (int n = 2; n < 4; ++n) { bf[n][0] = ldB(buf, n, 0); bf[n][1] = ldB(buf, n, 1); }
    stA0(ktc, buf); stB0(ktc, buf);
    bar();
    lgkm0_sb();
    __builtin_amdgcn_s_setprio(1);
    #pragma unroll
    for (int m = 0; m < MH; ++m)
      #pragma unroll
      for (int n = 2; n < 4; ++n)
        #pragma unroll
        for (int kk = 0; kk < 2; ++kk)
          acc[m][n] = __builtin_amdgcn_mfma_f32_16x16x32_bf16(af[m][kk], bf[n][kk], acc[m][n], 0, 0, 0);
    __builtin_amdgcn_s_setprio(0);
    vmw(1);
    bar();

    // ---- phase 2: read A-half1; stage B-n23 of kt+2; MFMA half1 x n01 (no wait needed) ----
    #pragma unroll
    for (int m = 0; m < MH; ++m) { af[m][0] = ldA(buf, MH + m, 0); af[m][1] = ldA(buf, MH + m, 1); }
    stB1(ktc, buf);
    bar();
    lgkm0_sb();
    __builtin_amdgcn_s_setprio(1);
    #pragma unroll
    for (int m = 0; m < MH; ++m)
      #pragma unroll
      for (int n = 0; n < 2; ++n)
        #pragma unroll
        for (int kk = 0; kk < 2; ++kk)
          acc[MH + m][n] = __builtin_amdgcn_mfma_f32_16x16x32_bf16(af[m][kk], bf[n][kk], acc[MH + m][n], 0, 0, 0);
    __builtin_amdgcn_s_setprio(0);
    bar();

    // ---- phase 3: stage A-half1 of kt+2; MFMA half1 x n23; wait for next tile A0/B01 ----
    stA1(ktc, buf);
    bar();
    lgkm0_sb();
    __builtin_amdgcn_s_setprio(1);
    #pragma unroll
    for (int m = 0; m < MH; ++m)
      #pragma unroll
      for (int n = 2; n < 4; ++n)
        #pragma unroll
        for (int kk = 0; kk < 2; ++kk)
          acc[MH + m][n] = __builtin_amdgcn_mfma_f32_16x16x32_bf16(af[m][kk], bf[n][kk], acc[MH + m][n], 0, 0, 0);
    __builtin_amdgcn_s_setprio(0);
    vmw(2);
    bar();
  }

  // epilogue: C/D layout col=lane&15, row=(lane>>4)*4+j
  #pragma unroll
  for (int mi = 0; mi < 2 * MH; ++mi)
    #pragma unroll
    for (int n = 0; n < 4; ++n)
      #pragma unroll
      for (int j = 0; j < 4; ++j) {
        size_t r = brow + wr * (BM / 2) + mi * 16 + g * 4 + j;
        size_t c = bcol + wc * 64 + n * 16 + ln;
        C[r * N + c] = (OutT)acc[mi][n][j];
      }
}

// ---------------- RoPE in place on QKV buffer [4096][3072] ----------------
__global__ void rope_kernel(__bf16* __restrict__ QKV, const float* __restrict__ cosb,
                            const float* __restrict__ sinb) {
  int gid = blockIdx.x * 256 + threadIdx.x;  // total 4096*20*16
  int p = gid & 15;
  int ht = gid >> 4;
  int hc = ht % 20;
  int tok = ht / 20;
  int s = tok & 1023;
  int colb = hc < 16 ? hc * 128 : 2048 + (hc - 16) * 128;
  __bf16* base = QKV + (size_t)tok * 3072 + colb;
  int d0 = p * 4;
  const float* cr = cosb + s * 128;
  const float* sr = sinb + s * 128;
  float x0[4], x1[4];
  #pragma unroll
  for (int j = 0; j < 4; ++j) {
    x0[j] = (float)base[d0 + j];
    x1[j] = (float)base[d0 + 64 + j];
  }
  #pragma unroll
  for (int j = 0; j < 4; ++j) {
    float n0 = x0[j] * cr[d0 + j] - x1[j] * sr[d0 + j];
    float n1 = x1[j] * cr[d0 + 64 + j] + x0[j] * sr[d0 + 64 + j];
    base[d0 + j] = (__bf16)n0;
    base[d0 + 64 + j] = (__bf16)n1;
  }
}

// ---------------- Flash attention (causal, GQA) — transposed orientation ----------------
__global__ __launch_bounds__(256, 2) void attn_kernel(const __bf16* __restrict__ QKV,
                                                      const __bf16* __restrict__ VT,
                                                      __bf16* __restrict__ AO) {
  __shared__ __bf16 Kl[2][64 * 128];
  __shared__ __bf16 Vt[128 * 64];
  __shared__ __bf16 Pl[4][16 * 72];

  const int tid = threadIdx.x, l = tid & 63, w = tid >> 6;
  const int h = blockIdx.y, b = blockIdx.z;
  const int kvh = h >> 2;
  const int g = l >> 4, ln = l & 15;
  const __bf16* VTg = VT + (size_t)(b * 4 + kvh) * 128 * 1024;
  const float scsc = 0.08838834764831845f;  // 1/sqrt(128)

  auto stageK = [&](int buf, int kt) {
    const __bf16* Kg = QKV + (size_t)(b * 1024 + kt * 64) * 3072 + 2048 + kvh * 128;
    #pragma unroll
    for (int i = 0; i < 4; ++i) {
      int r = i * 16 + (tid >> 4);
      int c = tid & 15;
      int csw = c ^ (r & 7);
      gload_lds16(Kg + (size_t)r * 3072 + csw * 8, (char*)&Kl[buf][0] + i * 4096 + tid * 16);
    }
  };
  auto stageV = [&](int kt) {
    #pragma unroll
    for (int i = 0; i < 4; ++i) {
      int ci = i * 256 + tid;
      int row = ci >> 3;
      int c = ci & 7;
      int csw = c ^ (row & 7);
      gload_lds16(VTg + (size_t)row * 1024 + kt * 64 + csw * 8, (char*)Vt + (size_t)ci * 16);
    }
  };

  #pragma unroll 1
  for (int pass = 0; pass < 2; ++pass) {
    const int qt = pass ? 15 - (int)blockIdx.x : (int)blockIdx.x;
    const size_t tokQ = (size_t)b * 1024 + qt * 64;

    bf16x8 qf[4];
    {
      const __bf16* qp = QKV + (tokQ + w * 16 + ln) * 3072 + h * 128;
      #pragma unroll
      for (int ks = 0; ks < 4; ++ks) qf[ks] = *(const bf16x8*)(qp + ks * 32 + g * 8);
    }

    float mrow = -1e30f, lrow = 0.f;
    f32x4 acco[8] = {};

    stageK(0, 0);
    int cur = 0;

    for (int kt = 0; kt <= qt; ++kt) {
      __syncthreads();

      stageV(kt);
      if (kt < qt) stageK(cur ^ 1, kt + 1);

      f32x4 accs[4] = {};
      __builtin_amdgcn_s_setprio(1);
      #pragma unroll
      for (int cb = 0; cb < 4; ++cb) {
        int row = cb * 16 + ln;
        #pragma unroll
        for (int ks = 0; ks < 4; ++ks) {
          bf16x8 kb = *(const bf16x8*)((const char*)&Kl[cur][0] + row * 256 +
                                       (((ks * 4 + g) ^ (row & 7)) * 16));
          accs[cb] = __builtin_amdgcn_mfma_f32_16x16x32_bf16(kb, qf[ks], accs[cb], 0, 0, 0);
        }
      }
      __builtin_amdgcn_s_setprio(0);

      const bool diag = (kt == qt);
      #pragma unroll
      for (int cb = 0; cb < 4; ++cb)
        #pragma unroll
        for (int j = 0; j < 4; ++j) {
          float s = accs[cb][j] * scsc;
          if (diag && (cb * 16 + g * 4 + j > w * 16 + ln)) s = -1e30f;
          accs[cb][j] = s;
        }

      float mt = accs[0][0];
      #pragma unroll
      for (int cb = 0; cb < 4; ++cb)
        #pragma unroll
        for (int j = 0; j < 4; ++j) mt = fmaxf(mt, accs[cb][j]);
      mt = fmaxf(mt, __shfl_xor(mt, 16, 64));
      mt = fmaxf(mt, __shfl_xor(mt, 32, 64));
      float mnew = fmaxf(mrow, mt);
      float corr = __expf(mrow - mnew);
      mrow = mnew;
      float rs = 0.f;
      #pragma unroll
      for (int cb = 0; cb < 4; ++cb)
        #pragma unroll
        for (int j = 0; j < 4; ++j) {
          float p = __expf(accs[cb][j] - mnew);
          accs[cb][j] = p;
          rs += p;
        }
      rs += __shfl_xor(rs, 16, 64);
      rs += __shfl_xor(rs, 32, 64);
      lrow = lrow * corr + rs;
      #pragma unroll
      for (int n = 0; n < 8; ++n)
        #pragma unroll
        for (int j = 0; j < 4; ++j) acco[n][j] *= corr;

      #pragma unroll
      for (int cb = 0; cb < 4; ++cb) {
        bf16x4 pw;
        #pragma unroll
        for (int j = 0; j < 4; ++j) pw[j] = (__bf16)accs[cb][j];
        *(bf16x4*)(&Pl[w][ln * 72 + cb * 16 + g * 4]) = pw;
      }

      __syncthreads();

      __builtin_amdgcn_s_setprio(1);
      #pragma unroll
      for (int sc = 0; sc < 2; ++sc) {
        bf16x8 pa = *(const bf16x8*)(&Pl[w][ln * 72 + sc * 32 + g * 8]);
        #pragma unroll
        for (int n = 0; n < 8; ++n) {
          int row = n * 16 + ln;
          bf16x8 vb = *(const bf16x8*)((const char*)Vt + row * 128 +
                                       (((sc * 4 + g) ^ (row & 7)) * 16));
          acco[n] = __builtin_amdgcn_mfma_f32_16x16x32_bf16(vb, pa, acco[n], 0, 0, 0);
        }
      }
      __builtin_amdgcn_s_setprio(0);
      cur ^= 1;
    }

    float rl = 1.f / lrow;
    size_t r = tokQ + w * 16 + ln;
    #pragma unroll
    for (int n = 0; n < 8; ++n) {
      bf16x4 ov;
      #pragma unroll
      for (int j = 0; j < 4; ++j) ov[j] = (__bf16)(acco[n][j] * rl);
      *(bf16x4*)(&AO[r * 2048 + h * 128 + n * 16 + g * 4]) = ov;
    }
  }
}

// ---------------- launch ----------------
extern "C" void kernel_launch(void* const* d_in, const int* in_sizes, int n_in,
                              void* d_out, int out_size, void* d_ws, size_t ws_size,
                              hipStream_t stream) {
  const float* x    = (const float*)d_in[0];
  const float* cosb = (const float*)d_in[1];
  const float* sinb = (const float*)d_in[2];
  const float* wq   = (const float*)d_in[3];
  const float* wk   = (const float*)d_in[4];
  const float* wv   = (const float*)d_in[5];
  const float* wo   = (const float*)d_in[6];
  float* out = (float*)d_out;

  char* ws = (char*)d_ws;
  const size_t OFF_XB    = 0;                       // 4096*2048 bf16 = 16 MiB (dead after gemm#1)
  const size_t OFF_WQKVT = OFF_XB + 16777216;       // 3072*2048 bf16 = 12 MiB
  const size_t OFF_WOT   = OFF_WQKVT + 12582912;    // 2048*2048 bf16 = 8 MiB
  const size_t OFF_QKV   = OFF_WOT + 8388608;       // 4096*3072 bf16 = 24 MiB
  const size_t OFF_AO    = OFF_QKV + 25165824;      // 4096*2048 bf16 = 16 MiB
  const size_t OFF_VT    = OFF_XB;                  // 16*128*1024 bf16 = 4 MiB, aliases Xb

  __bf16* Xb    = (__bf16*)(ws + OFF_XB);
  __bf16* WqkvT = (__bf16*)(ws + OFF_WQKVT);
  __bf16* WoT   = (__bf16*)(ws + OFF_WOT);
  __bf16* QKVb  = (__bf16*)(ws + OFF_QKV);
  __bf16* AOb   = (__bf16*)(ws + OFF_AO);
  __bf16* VTb   = (__bf16*)(ws + OFF_VT);

  // 1. convert x
  cvt_kernel<<<4096 * 2048 / 8 / 256, 256, 0, stream>>>(x, Xb, 4096 * 2048);
  // 2. transpose-convert weights
  tcvt_kernel<<<dim3(64, 64), 256, 0, stream>>>(wq, WqkvT, 2048, 2048);
  tcvt_kernel<<<dim3(16, 64), 256, 0, stream>>>(wk, WqkvT + (size_t)2048 * 2048, 2048, 512);
  tcvt_kernel<<<dim3(16, 64), 256, 0, stream>>>(wv, WqkvT + (size_t)2560 * 2048, 2048, 512);
  tcvt_kernel<<<dim3(64, 64), 256, 0, stream>>>(wo, WoT, 2048, 2048);
  // 3. QKV projection: 256x256 tiles, 12x16 = 192 blocks
  gemm8p<256, __bf16><<<dim3(12, 16), 512, 0, stream>>>(Xb, WqkvT, QKVb, 4096, 3072, 2048);
  // 4. transpose V into VT (V is not RoPE'd)
  vt_kernel<<<dim3(32, 4, 16), 256, 0, stream>>>(QKVb, VTb);
  // 5. RoPE in place (q + k)
  rope_kernel<<<4096 * 20 * 16 / 256, 256, 0, stream>>>(QKVb, cosb, sinb);
  // 6. attention: Q-tile 64, balanced pairs (x, 15-x)
  attn_kernel<<<dim3(8, 16, 4), 256, 0, stream>>>(QKVb, VTb, AOb);
  // 7. output projection: 128x256 tiles, 8x32 = 256 blocks (full chip)
  gemm8p<128, float><<<dim3(8, 32), 512, 0, stream>>>(AOb, WoT, out, 4096, 2048, 2048);
}

// Round 10
// 172.293 us; speedup vs baseline: 1.4364x; 1.0174x over previous
//
#include <hip/hip_runtime.h>

typedef __attribute__((ext_vector_type(8))) __bf16 bf16x8;
typedef __attribute__((ext_vector_type(4))) __bf16 bf16x4;
typedef __attribute__((ext_vector_type(4))) float f32x4;

#define DEV static __device__ __forceinline__

DEV void gload_lds16(const void* g, void* l) {
  __builtin_amdgcn_global_load_lds((const __attribute__((address_space(1))) void*)g,
                                   (__attribute__((address_space(3))) void*)l, 16, 0, 0);
}

DEV void lgkm0_sb() {
  asm volatile("s_waitcnt lgkmcnt(0)" ::: "memory");
  __builtin_amdgcn_sched_barrier(0);
}

// ---------------- convert x -> bf16 ----------------
__global__ void cvt_kernel(const float* __restrict__ src, __bf16* __restrict__ dst, int n) {
  int i = (blockIdx.x * 256 + threadIdx.x) * 8;
  if (i >= n) return;
  float4 a = *(const float4*)(src + i);
  float4 b = *(const float4*)(src + i + 4);
  bf16x8 o;
  o[0] = (__bf16)a.x; o[1] = (__bf16)a.y; o[2] = (__bf16)a.z; o[3] = (__bf16)a.w;
  o[4] = (__bf16)b.x; o[5] = (__bf16)b.y; o[6] = (__bf16)b.z; o[7] = (__bf16)b.w;
  *(bf16x8*)(dst + i) = o;
}

// ------------- transpose + convert weights: src K x N (f32) -> dst N x K (bf16) -------------
__global__ void tcvt_kernel(const float* __restrict__ src, __bf16* __restrict__ dst, int K, int N) {
  __shared__ float tile[32][33];
  int k0 = blockIdx.y * 32, n0 = blockIdx.x * 32;
  int tx = threadIdx.x & 31, ty = threadIdx.x >> 5;  // ty 0..7
  #pragma unroll
  for (int i = 0; i < 32; i += 8)
    tile[ty + i][tx] = src[(size_t)(k0 + ty + i) * N + n0 + tx];
  __syncthreads();
  #pragma unroll
  for (int i = 0; i < 32; i += 8)
    dst[(size_t)(n0 + ty + i) * K + k0 + tx] = (__bf16)tile[tx][ty + i];
}

// ------------- transpose V out of QKV: VT[(b*4+kvh)*128 + d][s] = V[b*1024+s][kvh*128+d] -------------
__global__ void vt_kernel(const __bf16* __restrict__ QKV, __bf16* __restrict__ VT) {
  __shared__ __bf16 t[32][33];
  int sx = blockIdx.x;  // 0..31 s-tile within batch
  int dx = blockIdx.y;  // 0..3  d-tile
  int bk = blockIdx.z;  // 0..15 (b*4+kvh)
  int b = bk >> 2, kvh = bk & 3;
  int tx = threadIdx.x & 31, ty = threadIdx.x >> 5;
  #pragma unroll
  for (int i = 0; i < 32; i += 8)
    t[ty + i][tx] = QKV[(size_t)(b * 1024 + sx * 32 + ty + i) * 3072 + 2560 + kvh * 128 + dx * 32 + tx];
  __syncthreads();
  #pragma unroll
  for (int i = 0; i < 32; i += 8)
    VT[((size_t)bk * 128 + dx * 32 + ty + i) * 1024 + sx * 32 + tx] = t[tx][ty + i];
}

// ================= 8-phase GEMM (generic BM x 256): out-proj =================
template <int BM, typename OutT>
__global__ __launch_bounds__(512, 2) void gemm8p(const __bf16* __restrict__ A,
                                                 const __bf16* __restrict__ Bt,
                                                 OutT* __restrict__ C,
                                                 int M, int N, int K) {
  constexpr int ABYTES = BM * 64 * 2;
  constexpr int BBYTES = 256 * 64 * 2;
  constexpr int MH = BM / 64;
  __shared__ alignas(1024) char smem[2 * (ABYTES + BBYTES)];

  const int tid = threadIdx.x;
  const int l = tid & 63, w = tid >> 6;
  const int wr = w >> 2, wc = w & 3;
  const int g = l >> 4, ln = l & 15;

  const int nbx = gridDim.x;
  const int nwg = nbx * gridDim.y;
  int lin = blockIdx.y * nbx + blockIdx.x;
  lin = (lin & 7) * (nwg >> 3) + (lin >> 3);  // bijective: nwg % 8 == 0
  const int brow = (lin / nbx) * BM, bcol = (lin % nbx) * 256;

  const __bf16* Ag = A + (size_t)brow * K;
  const __bf16* Bg = Bt + (size_t)bcol * K;
  const int NT = K / 64;

  auto Abuf = [&](int buf) -> char* { return smem + buf * ABYTES; };
  auto Bbuf = [&](int buf) -> char* { return smem + 2 * ABYTES + buf * BBYTES; };

  f32x4 acc[2 * MH][4] = {};

  auto chunk = [&](const __bf16* gb, char* lb, int ktc, int sub) {
    int r16 = l >> 2;
    int colb = ((l & 3) * 16) ^ (((l >> 5) & 1) << 5);
    int row = (sub >> 1) * 16 + r16;
    gload_lds16(gb + (size_t)row * K + ktc * 64 + (sub & 1) * 32 + (colb >> 1),
                lb + sub * 1024 + l * 16);
  };
  auto stA0 = [&](int ktc, int buf) {
    if constexpr (BM == 256) {
      #pragma unroll
      for (int i = 0; i < 2; ++i) { int idx = i * 8 + w; chunk(Ag, Abuf(buf), ktc, (idx >> 3) * 16 + (idx & 7)); }
    } else {
      chunk(Ag, Abuf(buf), ktc, (w >> 2) * 8 + (w & 3));
    }
  };
  auto stA1 = [&](int ktc, int buf) {
    if constexpr (BM == 256) {
      #pragma unroll
      for (int i = 0; i < 2; ++i) { int idx = i * 8 + w; chunk(Ag, Abuf(buf), ktc, 8 + (idx >> 3) * 16 + (idx & 7)); }
    } else {
      chunk(Ag, Abuf(buf), ktc, 4 + (w >> 2) * 8 + (w & 3));
    }
  };
  auto stB0 = [&](int ktc, int buf) {
    #pragma unroll
    for (int i = 0; i < 2; ++i) { int idx = i * 8 + w; chunk(Bg, Bbuf(buf), ktc, (idx >> 2) * 8 + (idx & 3)); }
  };
  auto stB1 = [&](int ktc, int buf) {
    #pragma unroll
    for (int i = 0; i < 2; ++i) { int idx = i * 8 + w; chunk(Bg, Bbuf(buf), ktc, 4 + (idx >> 2) * 8 + (idx & 3)); }
  };

  auto ldA = [&](int buf, int m, int kk) -> bf16x8 {
    int sub = (wr * (BM / 32) + m) * 2 + kk;
    return *(const bf16x8*)(Abuf(buf) + sub * 1024 + ln * 64 + ((g * 16) ^ (((ln >> 3) & 1) << 5)));
  };
  auto ldB = [&](int buf, int n, int kk) -> bf16x8 {
    int sub = (wc * 4 + n) * 2 + kk;
    return *(const bf16x8*)(Bbuf(buf) + sub * 1024 + ln * 64 + ((g * 16) ^ (((ln >> 3) & 1) << 5)));
  };

  auto vmw = [&](int which) {
    if constexpr (BM == 256) {
      if (which == 0) asm volatile("s_waitcnt vmcnt(10)" ::: "memory");
      else if (which == 1) asm volatile("s_waitcnt vmcnt(12)" ::: "memory");
      else asm volatile("s_waitcnt vmcnt(12)" ::: "memory");
    } else {
      if (which == 0) asm volatile("s_waitcnt vmcnt(7)" ::: "memory");
      else if (which == 1) asm volatile("s_waitcnt vmcnt(9)" ::: "memory");
      else asm volatile("s_waitcnt vmcnt(9)" ::: "memory");
    }
    __builtin_amdgcn_sched_barrier(0);
  };
  auto bar = [&]() {
    __builtin_amdgcn_sched_barrier(0);
    __builtin_amdgcn_s_barrier();
    __builtin_amdgcn_sched_barrier(0);
  };

  stA0(0, 0); stB0(0, 0); stB1(0, 0); stA1(0, 0);
  stA0(1, 1); stB0(1, 1); stB1(1, 1); stA1(1, 1);
  vmw(2);
  bar();

  bf16x8 af[MH][2], bf[4][2];

  for (int kt = 0; kt < NT; ++kt) {
    const int buf = kt & 1;
    const int ktc = (kt + 2) & 31;

    #pragma unroll
    for (int m = 0; m < MH; ++m) { af[m][0] = ldA(buf, m, 0); af[m][1] = ldA(buf, m, 1); }
    #pragma unroll
    for (int n = 0; n < 2; ++n) { bf[n][0] = ldB(buf, n, 0); bf[n][1] = ldB(buf, n, 1); }
    bar();
    lgkm0_sb();
    __builtin_amdgcn_s_setprio(1);
    #pragma unroll
    for (int m = 0; m < MH; ++m)
      #pragma unroll
      for (int n = 0; n < 2; ++n)
        #pragma unroll
        for (int kk = 0; kk < 2; ++kk)
          acc[m][n] = __builtin_amdgcn_mfma_f32_16x16x32_bf16(af[m][kk], bf[n][kk], acc[m][n], 0, 0, 0);
    __builtin_amdgcn_s_setprio(0);
    vmw(0);
    bar();

    #pragma unroll
    for (int n = 2; n < 4; ++n) { bf[n][0] = ldB(buf, n, 0); bf[n][1] = ldB(buf, n, 1); }
    stA0(ktc, buf); stB0(ktc, buf);
    bar();
    lgkm0_sb();
    __builtin_amdgcn_s_setprio(1);
    #pragma unroll
    for (int m = 0; m < MH; ++m)
      #pragma unroll
      for (int n = 2; n < 4; ++n)
        #pragma unroll
        for (int kk = 0; kk < 2; ++kk)
          acc[m][n] = __builtin_amdgcn_mfma_f32_16x16x32_bf16(af[m][kk], bf[n][kk], acc[m][n], 0, 0, 0);
    __builtin_amdgcn_s_setprio(0);
    vmw(1);
    bar();

    #pragma unroll
    for (int m = 0; m < MH; ++m) { af[m][0] = ldA(buf, MH + m, 0); af[m][1] = ldA(buf, MH + m, 1); }
    stB1(ktc, buf);
    bar();
    lgkm0_sb();
    __builtin_amdgcn_s_setprio(1);
    #pragma unroll
    for (int m = 0; m < MH; ++m)
      #pragma unroll
      for (int n = 0; n < 2; ++n)
        #pragma unroll
        for (int kk = 0; kk < 2; ++kk)
          acc[MH + m][n] = __builtin_amdgcn_mfma_f32_16x16x32_bf16(af[m][kk], bf[n][kk], acc[MH + m][n], 0, 0, 0);
    __builtin_amdgcn_s_setprio(0);
    bar();

    stA1(ktc, buf);
    bar();
    lgkm0_sb();
    __builtin_amdgcn_s_setprio(1);
    #pragma unroll
    for (int m = 0; m < MH; ++m)
      #pragma unroll
      for (int n = 2; n < 4; ++n)
        #pragma unroll
        for (int kk = 0; kk < 2; ++kk)
          acc[MH + m][n] = __builtin_amdgcn_mfma_f32_16x16x32_bf16(af[m][kk], bf[n][kk], acc[MH + m][n], 0, 0, 0);
    __builtin_amdgcn_s_setprio(0);
    vmw(2);
    bar();
  }

  #pragma unroll
  for (int mi = 0; mi < 2 * MH; ++mi)
    #pragma unroll
    for (int n = 0; n < 4; ++n)
      #pragma unroll
      for (int j = 0; j < 4; ++j) {
        size_t r = brow + wr * (BM / 2) + mi * 16 + g * 4 + j;
        size_t c = bcol + wc * 64 + n * 16 + ln;
        C[r * N + c] = (OutT)acc[mi][n][j];
      }
}

// ================= 8-phase GEMM 256x192 (QKV): full 256-block chip fill =================
// 512 thr = 8 waves (2M x 4N); per-wave 128 rows x 48 cols (8 m-frags, 3 n-frags).
// B: 24 subtiles; n-groups {n0,n1} (16 subtiles, 2/thr) and {n2} (8 subtiles, 1/thr).
// Loads/tile/wave = 7, order [A0(2) Bg0(2) | Bg1(1) | A1(2)].
// Ledger: end-p0 vmcnt(9), end-p1 vmcnt(11), end-p2 none, end-p3 vmcnt(10), prologue vmcnt(10).
__global__ __launch_bounds__(512, 2) void gemm8p_qkv(const __bf16* __restrict__ A,
                                                     const __bf16* __restrict__ Bt,
                                                     __bf16* __restrict__ C,
                                                     int M, int N, int K) {
  constexpr int ABYTES = 256 * 64 * 2;   // 32 KB
  constexpr int BBYTES = 192 * 64 * 2;   // 24 KB
  __shared__ alignas(1024) char smem[2 * (ABYTES + BBYTES)];  // 112 KB

  const int tid = threadIdx.x;
  const int l = tid & 63, w = tid >> 6;
  const int wr = w >> 2, wc = w & 3;
  const int g = l >> 4, ln = l & 15;

  const int nbx = gridDim.x;  // 16
  const int nwg = nbx * gridDim.y;
  int lin = blockIdx.y * nbx + blockIdx.x;
  lin = (lin & 7) * (nwg >> 3) + (lin >> 3);  // bijective: 256 % 8 == 0
  const int brow = (lin / nbx) * 256, bcol = (lin % nbx) * 192;

  const __bf16* Ag = A + (size_t)brow * K;
  const __bf16* Bg = Bt + (size_t)bcol * K;
  const int NT = K / 64;  // 32

  auto Abuf = [&](int buf) -> char* { return smem + buf * ABYTES; };
  auto Bbuf = [&](int buf) -> char* { return smem + 2 * ABYTES + buf * BBYTES; };

  f32x4 acc[8][3] = {};

  auto chunk = [&](const __bf16* gb, char* lb, int ktc, int sub) {
    int r16 = l >> 2;
    int colb = ((l & 3) * 16) ^ (((l >> 5) & 1) << 5);
    int row = (sub >> 1) * 16 + r16;
    gload_lds16(gb + (size_t)row * K + ktc * 64 + (sub & 1) * 32 + (colb >> 1),
                lb + sub * 1024 + l * 16);
  };
  auto stA0 = [&](int ktc, int buf) {  // A subtiles 0..15 (2/thr)
    #pragma unroll
    for (int i = 0; i < 2; ++i) { int idx = i * 8 + w; chunk(Ag, Abuf(buf), ktc, (idx >> 3) * 16 + (idx & 7)); }
  };
  auto stA1 = [&](int ktc, int buf) {  // A subtiles 16..31
    #pragma unroll
    for (int i = 0; i < 2; ++i) { int idx = i * 8 + w; chunk(Ag, Abuf(buf), ktc, 8 + (idx >> 3) * 16 + (idx & 7)); }
  };
  auto stBg0 = [&](int ktc, int buf) {  // n16 in {wc*3, wc*3+1}: 16 subtiles (2/thr)
    #pragma unroll
    for (int i = 0; i < 2; ++i) {
      int t = i * 8 + w;  // 0..15
      int sub = ((t >> 2) * 3 + ((t >> 1) & 1)) * 2 + (t & 1);
      chunk(Bg, Bbuf(buf), ktc, sub);
    }
  };
  auto stBg1 = [&](int ktc, int buf) {  // n16 in {wc*3+2}: 8 subtiles (1/thr)
    int sub = ((w >> 1) * 3 + 2) * 2 + (w & 1);
    chunk(Bg, Bbuf(buf), ktc, sub);
  };

  auto ldA = [&](int buf, int m, int kk) -> bf16x8 {
    int sub = (wr * 8 + m) * 2 + kk;
    return *(const bf16x8*)(Abuf(buf) + sub * 1024 + ln * 64 + ((g * 16) ^ (((ln >> 3) & 1) << 5)));
  };
  auto ldB = [&](int buf, int nf, int kk) -> bf16x8 {
    int sub = (wc * 3 + nf) * 2 + kk;
    return *(const bf16x8*)(Bbuf(buf) + sub * 1024 + ln * 64 + ((g * 16) ^ (((ln >> 3) & 1) << 5)));
  };

  auto bar = [&]() {
    __builtin_amdgcn_sched_barrier(0);
    __builtin_amdgcn_s_barrier();
    __builtin_amdgcn_sched_barrier(0);
  };

  // prologue: tiles 0,1 in per-tile order [A0 Bg0 Bg1 A1]
  stA0(0, 0); stBg0(0, 0); stBg1(0, 0); stA1(0, 0);
  stA0(1, 1); stBg0(1, 1); stBg1(1, 1); stA1(1, 1);
  asm volatile("s_waitcnt vmcnt(10)" ::: "memory");
  __builtin_amdgcn_sched_barrier(0);
  bar();

  bf16x8 af[4][2], bfv[3][2];

  for (int kt = 0; kt < NT; ++kt) {
    const int buf = kt & 1;
    const int ktc = (kt + 2) & 31;

    // ---- p0: read A-half0 (m0..3) + B n0,n1; MFMA 16; wait Bg1 ----
    #pragma unroll
    for (int m = 0; m < 4; ++m) { af[m][0] = ldA(buf, m, 0); af[m][1] = ldA(buf, m, 1); }
    #pragma unroll
    for (int nf = 0; nf < 2; ++nf) { bfv[nf][0] = ldB(buf, nf, 0); bfv[nf][1] = ldB(buf, nf, 1); }
    bar();
    lgkm0_sb();
    __builtin_amdgcn_s_setprio(1);
    #pragma unroll
    for (int m = 0; m < 4; ++m)
      #pragma unroll
      for (int nf = 0; nf < 2; ++nf)
        #pragma unroll
        for (int kk = 0; kk < 2; ++kk)
          acc[m][nf] = __builtin_amdgcn_mfma_f32_16x16x32_bf16(af[m][kk], bfv[nf][kk], acc[m][nf], 0, 0, 0);
    __builtin_amdgcn_s_setprio(0);
    asm volatile("s_waitcnt vmcnt(9)" ::: "memory");
    __builtin_amdgcn_sched_barrier(0);
    bar();

    // ---- p1: read B n2; stage A0+Bg0 of kt+2; MFMA 8; wait A1 ----
    bfv[2][0] = ldB(buf, 2, 0); bfv[2][1] = ldB(buf, 2, 1);
    stA0(ktc, buf); stBg0(ktc, buf);
    bar();
    lgkm0_sb();
    __builtin_amdgcn_s_setprio(1);
    #pragma unroll
    for (int m = 0; m < 4; ++m)
      #pragma unroll
      for (int kk = 0; kk < 2; ++kk)
        acc[m][2] = __builtin_amdgcn_mfma_f32_16x16x32_bf16(af[m][kk], bfv[2][kk], acc[m][2], 0, 0, 0);
    __builtin_amdgcn_s_setprio(0);
    asm volatile("s_waitcnt vmcnt(11)" ::: "memory");
    __builtin_amdgcn_sched_barrier(0);
    bar();

    // ---- p2: read A-half1 (m4..7); stage Bg1 of kt+2; MFMA 16 ----
    #pragma unroll
    for (int m = 0; m < 4; ++m) { af[m][0] = ldA(buf, 4 + m, 0); af[m][1] = ldA(buf, 4 + m, 1); }
    stBg1(ktc, buf);
    bar();
    lgkm0_sb();
    __builtin_amdgcn_s_setprio(1);
    #pragma unroll
    for (int m = 0; m < 4; ++m)
      #pragma unroll
      for (int nf = 0; nf < 2; ++nf)
        #pragma unroll
        for (int kk = 0; kk < 2; ++kk)
          acc[4 + m][nf] = __builtin_amdgcn_mfma_f32_16x16x32_bf16(af[m][kk], bfv[nf][kk], acc[4 + m][nf], 0, 0, 0);
    __builtin_amdgcn_s_setprio(0);
    bar();

    // ---- p3: stage A1 of kt+2; MFMA 8; wait next A0+Bg0 ----
    stA1(ktc, buf);
    bar();
    lgkm0_sb();
    __builtin_amdgcn_s_setprio(1);
    #pragma unroll
    for (int m = 0; m < 4; ++m)
      #pragma unroll
      for (int kk = 0; kk < 2; ++kk)
        acc[4 + m][2] = __builtin_amdgcn_mfma_f32_16x16x32_bf16(af[m][kk], bfv[2][kk], acc[4 + m][2], 0, 0, 0);
    __builtin_amdgcn_s_setprio(0);
    asm volatile("s_waitcnt vmcnt(10)" ::: "memory");
    __builtin_amdgcn_sched_barrier(0);
    bar();
  }

  // epilogue: C/D layout col=lane&15, row=(lane>>4)*4+j
  #pragma unroll
  for (int mi = 0; mi < 8; ++mi)
    #pragma unroll
    for (int nf = 0; nf < 3; ++nf)
      #pragma unroll
      for (int j = 0; j < 4; ++j) {
        size_t r = brow + wr * 128 + mi * 16 + g * 4 + j;
        size_t c = bcol + wc * 48 + nf * 16 + ln;
        C[r * N + c] = (__bf16)acc[mi][nf][j];
      }
}

// ---------------- RoPE in place on QKV buffer [4096][3072] ----------------
__global__ void rope_kernel(__bf16* __restrict__ QKV, const float* __restrict__ cosb,
                            const float* __restrict__ sinb) {
  int gid = blockIdx.x * 256 + threadIdx.x;  // total 4096*20*16
  int p = gid & 15;
  int ht = gid >> 4;
  int hc = ht % 20;
  int tok = ht / 20;
  int s = tok & 1023;
  int colb = hc < 16 ? hc * 128 : 2048 + (hc - 16) * 128;
  __bf16* base = QKV + (size_t)tok * 3072 + colb;
  int d0 = p * 4;
  const float* cr = cosb + s * 128;
  const float* sr = sinb + s * 128;
  float x0[4], x1[4];
  #pragma unroll
  for (int j = 0; j < 4; ++j) {
    x0[j] = (float)base[d0 + j];
    x1[j] = (float)base[d0 + 64 + j];
  }
  #pragma unroll
  for (int j = 0; j < 4; ++j) {
    float n0 = x0[j] * cr[d0 + j] - x1[j] * sr[d0 + j];
    float n1 = x1[j] * cr[d0 + 64 + j] + x0[j] * sr[d0 + 64 + j];
    base[d0 + j] = (__bf16)n0;
    base[d0 + 64 + j] = (__bf16)n1;
  }
}

// ---------------- Flash attention (causal, GQA) — transposed orientation ----------------
__global__ __launch_bounds__(256, 2) void attn_kernel(const __bf16* __restrict__ QKV,
                                                      const __bf16* __restrict__ VT,
                                                      __bf16* __restrict__ AO) {
  __shared__ __bf16 Kl[2][64 * 128];
  __shared__ __bf16 Vt[128 * 64];
  __shared__ __bf16 Pl[4][16 * 72];

  const int tid = threadIdx.x, l = tid & 63, w = tid >> 6;
  const int h = blockIdx.y, b = blockIdx.z;
  const int kvh = h >> 2;
  const int g = l >> 4, ln = l & 15;
  const __bf16* VTg = VT + (size_t)(b * 4 + kvh) * 128 * 1024;
  const float scsc = 0.08838834764831845f;  // 1/sqrt(128)

  auto stageK = [&](int buf, int kt) {
    const __bf16* Kg = QKV + (size_t)(b * 1024 + kt * 64) * 3072 + 2048 + kvh * 128;
    #pragma unroll
    for (int i = 0; i < 4; ++i) {
      int r = i * 16 + (tid >> 4);
      int c = tid & 15;
      int csw = c ^ (r & 7);
      gload_lds16(Kg + (size_t)r * 3072 + csw * 8, (char*)&Kl[buf][0] + i * 4096 + tid * 16);
    }
  };
  auto stageV = [&](int kt) {
    #pragma unroll
    for (int i = 0; i < 4; ++i) {
      int ci = i * 256 + tid;
      int row = ci >> 3;
      int c = ci & 7;
      int csw = c ^ (row & 7);
      gload_lds16(VTg + (size_t)row * 1024 + kt * 64 + csw * 8, (char*)Vt + (size_t)ci * 16);
    }
  };

  #pragma unroll 1
  for (int pass = 0; pass < 2; ++pass) {
    const int qt = pass ? 15 - (int)blockIdx.x : (int)blockIdx.x;
    const size_t tokQ = (size_t)b * 1024 + qt * 64;

    bf16x8 qf[4];
    {
      const __bf16* qp = QKV + (tokQ + w * 16 + ln) * 3072 + h * 128;
      #pragma unroll
      for (int ks = 0; ks < 4; ++ks) qf[ks] = *(const bf16x8*)(qp + ks * 32 + g * 8);
    }

    float mrow = -1e30f, lrow = 0.f;
    f32x4 acco[8] = {};

    stageK(0, 0);
    int cur = 0;

    for (int kt = 0; kt <= qt; ++kt) {
      __syncthreads();

      stageV(kt);
      if (kt < qt) stageK(cur ^ 1, kt + 1);

      f32x4 accs[4] = {};
      __builtin_amdgcn_s_setprio(1);
      #pragma unroll
      for (int cb = 0; cb < 4; ++cb) {
        int row = cb * 16 + ln;
        #pragma unroll
        for (int ks = 0; ks < 4; ++ks) {
          bf16x8 kb = *(const bf16x8*)((const char*)&Kl[cur][0] + row * 256 +
                                       (((ks * 4 + g) ^ (row & 7)) * 16));
          accs[cb] = __builtin_amdgcn_mfma_f32_16x16x32_bf16(kb, qf[ks], accs[cb], 0, 0, 0);
        }
      }
      __builtin_amdgcn_s_setprio(0);

      const bool diag = (kt == qt);
      #pragma unroll
      for (int cb = 0; cb < 4; ++cb)
        #pragma unroll
        for (int j = 0; j < 4; ++j) {
          float s = accs[cb][j] * scsc;
          if (diag && (cb * 16 + g * 4 + j > w * 16 + ln)) s = -1e30f;
          accs[cb][j] = s;
        }

      float mt = accs[0][0];
      #pragma unroll
      for (int cb = 0; cb < 4; ++cb)
        #pragma unroll
        for (int j = 0; j < 4; ++j) mt = fmaxf(mt, accs[cb][j]);
      mt = fmaxf(mt, __shfl_xor(mt, 16, 64));
      mt = fmaxf(mt, __shfl_xor(mt, 32, 64));
      float mnew = fmaxf(mrow, mt);
      float corr = __expf(mrow - mnew);
      mrow = mnew;
      float rs = 0.f;
      #pragma unroll
      for (int cb = 0; cb < 4; ++cb)
        #pragma unroll
        for (int j = 0; j < 4; ++j) {
          float p = __expf(accs[cb][j] - mnew);
          accs[cb][j] = p;
          rs += p;
        }
      rs += __shfl_xor(rs, 16, 64);
      rs += __shfl_xor(rs, 32, 64);
      lrow = lrow * corr + rs;
      #pragma unroll
      for (int n = 0; n < 8; ++n)
        #pragma unroll
        for (int j = 0; j < 4; ++j) acco[n][j] *= corr;

      #pragma unroll
      for (int cb = 0; cb < 4; ++cb) {
        bf16x4 pw;
        #pragma unroll
        for (int j = 0; j < 4; ++j) pw[j] = (__bf16)accs[cb][j];
        *(bf16x4*)(&Pl[w][ln * 72 + cb * 16 + g * 4]) = pw;
      }

      __syncthreads();

      __builtin_amdgcn_s_setprio(1);
      #pragma unroll
      for (int sc = 0; sc < 2; ++sc) {
        bf16x8 pa = *(const bf16x8*)(&Pl[w][ln * 72 + sc * 32 + g * 8]);
        #pragma unroll
        for (int n = 0; n < 8; ++n) {
          int row = n * 16 + ln;
          bf16x8 vb = *(const bf16x8*)((const char*)Vt + row * 128 +
                                       (((sc * 4 + g) ^ (row & 7)) * 16));
          acco[n] = __builtin_amdgcn_mfma_f32_16x16x32_bf16(vb, pa, acco[n], 0, 0, 0);
        }
      }
      __builtin_amdgcn_s_setprio(0);
      cur ^= 1;
    }

    float rl = 1.f / lrow;
    size_t r = tokQ + w * 16 + ln;
    #pragma unroll
    for (int n = 0; n < 8; ++n) {
      bf16x4 ov;
      #pragma unroll
      for (int j = 0; j < 4; ++j) ov[j] = (__bf16)(acco[n][j] * rl);
      *(bf16x4*)(&AO[r * 2048 + h * 128 + n * 16 + g * 4]) = ov;
    }
  }
}

// ---------------- launch ----------------
extern "C" void kernel_launch(void* const* d_in, const int* in_sizes, int n_in,
                              void* d_out, int out_size, void* d_ws, size_t ws_size,
                              hipStream_t stream) {
  const float* x    = (const float*)d_in[0];
  const float* cosb = (const float*)d_in[1];
  const float* sinb = (const float*)d_in[2];
  const float* wq   = (const float*)d_in[3];
  const float* wk   = (const float*)d_in[4];
  const float* wv   = (const float*)d_in[5];
  const float* wo   = (const float*)d_in[6];
  float* out = (float*)d_out;

  char* ws = (char*)d_ws;
  const size_t OFF_XB    = 0;                       // 4096*2048 bf16 = 16 MiB (dead after gemm#1)
  const size_t OFF_WQKVT = OFF_XB + 16777216;       // 3072*2048 bf16 = 12 MiB
  const size_t OFF_WOT   = OFF_WQKVT + 12582912;    // 2048*2048 bf16 = 8 MiB
  const size_t OFF_QKV   = OFF_WOT + 8388608;       // 4096*3072 bf16 = 24 MiB
  const size_t OFF_AO    = OFF_QKV + 25165824;      // 4096*2048 bf16 = 16 MiB
  const size_t OFF_VT    = OFF_XB;                  // 16*128*1024 bf16 = 4 MiB, aliases Xb

  __bf16* Xb    = (__bf16*)(ws + OFF_XB);
  __bf16* WqkvT = (__bf16*)(ws + OFF_WQKVT);
  __bf16* WoT   = (__bf16*)(ws + OFF_WOT);
  __bf16* QKVb  = (__bf16*)(ws + OFF_QKV);
  __bf16* AOb   = (__bf16*)(ws + OFF_AO);
  __bf16* VTb   = (__bf16*)(ws + OFF_VT);

  // 1. convert x
  cvt_kernel<<<4096 * 2048 / 8 / 256, 256, 0, stream>>>(x, Xb, 4096 * 2048);
  // 2. transpose-convert weights
  tcvt_kernel<<<dim3(64, 64), 256, 0, stream>>>(wq, WqkvT, 2048, 2048);
  tcvt_kernel<<<dim3(16, 64), 256, 0, stream>>>(wk, WqkvT + (size_t)2048 * 2048, 2048, 512);
  tcvt_kernel<<<dim3(16, 64), 256, 0, stream>>>(wv, WqkvT + (size_t)2560 * 2048, 2048, 512);
  tcvt_kernel<<<dim3(64, 64), 256, 0, stream>>>(wo, WoT, 2048, 2048);
  // 3. QKV projection: 256x192 tiles, 16x16 = 256 blocks (full chip fill)
  gemm8p_qkv<<<dim3(16, 16), 512, 0, stream>>>(Xb, WqkvT, QKVb, 4096, 3072, 2048);
  // 4. transpose V into VT (V is not RoPE'd)
  vt_kernel<<<dim3(32, 4, 16), 256, 0, stream>>>(QKVb, VTb);
  // 5. RoPE in place (q + k)
  rope_kernel<<<4096 * 20 * 16 / 256, 256, 0, stream>>>(QKVb, cosb, sinb);
  // 6. attention: Q-tile 64, balanced pairs (x, 15-x)
  attn_kernel<<<dim3(8, 16, 4), 256, 0, stream>>>(QKVb, VTb, AOb);
  // 7. output projection: 128x256 tiles, 8x32 = 256 blocks (full chip)
  gemm8p<128, float><<<dim3(8, 32), 512, 0, stream>>>(AOb, WoT, out, 4096, 2048, 2048);
}

// Round 11
// 171.475 us; speedup vs baseline: 1.4433x; 1.0048x over previous
//
#include <hip/hip_runtime.h>

typedef __attribute__((ext_vector_type(8))) __bf16 bf16x8;
typedef __attribute__((ext_vector_type(4))) __bf16 bf16x4;
typedef __attribute__((ext_vector_type(4))) float f32x4;

#define DEV static __device__ __forceinline__

DEV void gload_lds16(const void* g, void* l) {
  __builtin_amdgcn_global_load_lds((const __attribute__((address_space(1))) void*)g,
                                   (__attribute__((address_space(3))) void*)l, 16, 0, 0);
}

DEV void lgkm0_sb() {
  asm volatile("s_waitcnt lgkmcnt(0)" ::: "memory");
  __builtin_amdgcn_sched_barrier(0);
}

// ---------------- convert x -> bf16 ----------------
__global__ void cvt_kernel(const float* __restrict__ src, __bf16* __restrict__ dst, int n) {
  int i = (blockIdx.x * 256 + threadIdx.x) * 8;
  if (i >= n) return;
  float4 a = *(const float4*)(src + i);
  float4 b = *(const float4*)(src + i + 4);
  bf16x8 o;
  o[0] = (__bf16)a.x; o[1] = (__bf16)a.y; o[2] = (__bf16)a.z; o[3] = (__bf16)a.w;
  o[4] = (__bf16)b.x; o[5] = (__bf16)b.y; o[6] = (__bf16)b.z; o[7] = (__bf16)b.w;
  *(bf16x8*)(dst + i) = o;
}

// ------------- transpose + convert weights: src K x N (f32) -> dst N x K (bf16) -------------
__global__ void tcvt_kernel(const float* __restrict__ src, __bf16* __restrict__ dst, int K, int N) {
  __shared__ float tile[32][33];
  int k0 = blockIdx.y * 32, n0 = blockIdx.x * 32;
  int tx = threadIdx.x & 31, ty = threadIdx.x >> 5;  // ty 0..7
  #pragma unroll
  for (int i = 0; i < 32; i += 8)
    tile[ty + i][tx] = src[(size_t)(k0 + ty + i) * N + n0 + tx];
  __syncthreads();
  #pragma unroll
  for (int i = 0; i < 32; i += 8)
    dst[(size_t)(n0 + ty + i) * K + k0 + tx] = (__bf16)tile[tx][ty + i];
}

// ------------- transpose V out of QKV: VT[(b*4+kvh)*128 + d][s] = V[b*1024+s][kvh*128+d] -------------
__global__ void vt_kernel(const __bf16* __restrict__ QKV, __bf16* __restrict__ VT) {
  __shared__ __bf16 t[32][33];
  int sx = blockIdx.x;  // 0..31 s-tile within batch
  int dx = blockIdx.y;  // 0..3  d-tile
  int bk = blockIdx.z;  // 0..15 (b*4+kvh)
  int b = bk >> 2, kvh = bk & 3;
  int tx = threadIdx.x & 31, ty = threadIdx.x >> 5;
  #pragma unroll
  for (int i = 0; i < 32; i += 8)
    t[ty + i][tx] = QKV[(size_t)(b * 1024 + sx * 32 + ty + i) * 3072 + 2560 + kvh * 128 + dx * 32 + tx];
  __syncthreads();
  #pragma unroll
  for (int i = 0; i < 32; i += 8)
    VT[((size_t)bk * 128 + dx * 32 + ty + i) * 1024 + sx * 32 + tx] = t[tx][ty + i];
}

// ================= 8-phase GEMM 256x192 (QKV) — unchanged from R10 (passing) =================
__global__ __launch_bounds__(512, 2) void gemm8p_qkv(const __bf16* __restrict__ A,
                                                     const __bf16* __restrict__ Bt,
                                                     __bf16* __restrict__ C,
                                                     int M, int N, int K) {
  constexpr int ABYTES = 256 * 64 * 2;   // 32 KB
  constexpr int BBYTES = 192 * 64 * 2;   // 24 KB
  __shared__ alignas(1024) char smem[2 * (ABYTES + BBYTES)];  // 112 KB

  const int tid = threadIdx.x;
  const int l = tid & 63, w = tid >> 6;
  const int wr = w >> 2, wc = w & 3;
  const int g = l >> 4, ln = l & 15;

  const int nbx = gridDim.x;  // 16
  const int nwg = nbx * gridDim.y;
  int lin = blockIdx.y * nbx + blockIdx.x;
  lin = (lin & 7) * (nwg >> 3) + (lin >> 3);  // bijective: 256 % 8 == 0
  const int brow = (lin / nbx) * 256, bcol = (lin % nbx) * 192;

  const __bf16* Ag = A + (size_t)brow * K;
  const __bf16* Bg = Bt + (size_t)bcol * K;
  const int NT = K / 64;  // 32

  auto Abuf = [&](int buf) -> char* { return smem + buf * ABYTES; };
  auto Bbuf = [&](int buf) -> char* { return smem + 2 * ABYTES + buf * BBYTES; };

  f32x4 acc[8][3] = {};

  auto chunk = [&](const __bf16* gb, char* lb, int ktc, int sub) {
    int r16 = l >> 2;
    int colb = ((l & 3) * 16) ^ (((l >> 5) & 1) << 5);
    int row = (sub >> 1) * 16 + r16;
    gload_lds16(gb + (size_t)row * K + ktc * 64 + (sub & 1) * 32 + (colb >> 1),
                lb + sub * 1024 + l * 16);
  };
  auto stA0 = [&](int ktc, int buf) {
    #pragma unroll
    for (int i = 0; i < 2; ++i) { int idx = i * 8 + w; chunk(Ag, Abuf(buf), ktc, (idx >> 3) * 16 + (idx & 7)); }
  };
  auto stA1 = [&](int ktc, int buf) {
    #pragma unroll
    for (int i = 0; i < 2; ++i) { int idx = i * 8 + w; chunk(Ag, Abuf(buf), ktc, 8 + (idx >> 3) * 16 + (idx & 7)); }
  };
  auto stBg0 = [&](int ktc, int buf) {
    #pragma unroll
    for (int i = 0; i < 2; ++i) {
      int t = i * 8 + w;
      int sub = ((t >> 2) * 3 + ((t >> 1) & 1)) * 2 + (t & 1);
      chunk(Bg, Bbuf(buf), ktc, sub);
    }
  };
  auto stBg1 = [&](int ktc, int buf) {
    int sub = ((w >> 1) * 3 + 2) * 2 + (w & 1);
    chunk(Bg, Bbuf(buf), ktc, sub);
  };

  auto ldA = [&](int buf, int m, int kk) -> bf16x8 {
    int sub = (wr * 8 + m) * 2 + kk;
    return *(const bf16x8*)(Abuf(buf) + sub * 1024 + ln * 64 + ((g * 16) ^ (((ln >> 3) & 1) << 5)));
  };
  auto ldB = [&](int buf, int nf, int kk) -> bf16x8 {
    int sub = (wc * 3 + nf) * 2 + kk;
    return *(const bf16x8*)(Bbuf(buf) + sub * 1024 + ln * 64 + ((g * 16) ^ (((ln >> 3) & 1) << 5)));
  };

  auto bar = [&]() {
    __builtin_amdgcn_sched_barrier(0);
    __builtin_amdgcn_s_barrier();
    __builtin_amdgcn_sched_barrier(0);
  };

  stA0(0, 0); stBg0(0, 0); stBg1(0, 0); stA1(0, 0);
  stA0(1, 1); stBg0(1, 1); stBg1(1, 1); stA1(1, 1);
  asm volatile("s_waitcnt vmcnt(10)" ::: "memory");
  __builtin_amdgcn_sched_barrier(0);
  bar();

  bf16x8 af[4][2], bfv[3][2];

  for (int kt = 0; kt < NT; ++kt) {
    const int buf = kt & 1;
    const int ktc = (kt + 2) & 31;

    #pragma unroll
    for (int m = 0; m < 4; ++m) { af[m][0] = ldA(buf, m, 0); af[m][1] = ldA(buf, m, 1); }
    #pragma unroll
    for (int nf = 0; nf < 2; ++nf) { bfv[nf][0] = ldB(buf, nf, 0); bfv[nf][1] = ldB(buf, nf, 1); }
    bar();
    lgkm0_sb();
    __builtin_amdgcn_s_setprio(1);
    #pragma unroll
    for (int m = 0; m < 4; ++m)
      #pragma unroll
      for (int nf = 0; nf < 2; ++nf)
        #pragma unroll
        for (int kk = 0; kk < 2; ++kk)
          acc[m][nf] = __builtin_amdgcn_mfma_f32_16x16x32_bf16(af[m][kk], bfv[nf][kk], acc[m][nf], 0, 0, 0);
    __builtin_amdgcn_s_setprio(0);
    asm volatile("s_waitcnt vmcnt(9)" ::: "memory");
    __builtin_amdgcn_sched_barrier(0);
    bar();

    bfv[2][0] = ldB(buf, 2, 0); bfv[2][1] = ldB(buf, 2, 1);
    stA0(ktc, buf); stBg0(ktc, buf);
    bar();
    lgkm0_sb();
    __builtin_amdgcn_s_setprio(1);
    #pragma unroll
    for (int m = 0; m < 4; ++m)
      #pragma unroll
      for (int kk = 0; kk < 2; ++kk)
        acc[m][2] = __builtin_amdgcn_mfma_f32_16x16x32_bf16(af[m][kk], bfv[2][kk], acc[m][2], 0, 0, 0);
    __builtin_amdgcn_s_setprio(0);
    asm volatile("s_waitcnt vmcnt(11)" ::: "memory");
    __builtin_amdgcn_sched_barrier(0);
    bar();

    #pragma unroll
    for (int m = 0; m < 4; ++m) { af[m][0] = ldA(buf, 4 + m, 0); af[m][1] = ldA(buf, 4 + m, 1); }
    stBg1(ktc, buf);
    bar();
    lgkm0_sb();
    __builtin_amdgcn_s_setprio(1);
    #pragma unroll
    for (int m = 0; m < 4; ++m)
      #pragma unroll
      for (int nf = 0; nf < 2; ++nf)
        #pragma unroll
        for (int kk = 0; kk < 2; ++kk)
          acc[4 + m][nf] = __builtin_amdgcn_mfma_f32_16x16x32_bf16(af[m][kk], bfv[nf][kk], acc[4 + m][nf], 0, 0, 0);
    __builtin_amdgcn_s_setprio(0);
    bar();

    stA1(ktc, buf);
    bar();
    lgkm0_sb();
    __builtin_amdgcn_s_setprio(1);
    #pragma unroll
    for (int m = 0; m < 4; ++m)
      #pragma unroll
      for (int kk = 0; kk < 2; ++kk)
        acc[4 + m][2] = __builtin_amdgcn_mfma_f32_16x16x32_bf16(af[m][kk], bfv[2][kk], acc[4 + m][2], 0, 0, 0);
    __builtin_amdgcn_s_setprio(0);
    asm volatile("s_waitcnt vmcnt(10)" ::: "memory");
    __builtin_amdgcn_sched_barrier(0);
    bar();
  }

  #pragma unroll
  for (int mi = 0; mi < 8; ++mi)
    #pragma unroll
    for (int nf = 0; nf < 3; ++nf)
      #pragma unroll
      for (int j = 0; j < 4; ++j) {
        size_t r = brow + wr * 128 + mi * 16 + g * 4 + j;
        size_t c = bcol + wc * 48 + nf * 16 + ln;
        C[r * N + c] = (__bf16)acc[mi][nf][j];
      }
}

// ================= 2-phase GEMM 256x128 (out-proj): full fill, fat phases =================
// 512 thr = 8 waves (4M x 2N); per-wave 64x64 (4 m-frags x 4 n-frags), 32 MFMA/tile.
// 2 phases/K-tile x 16 MFMA, 4 barriers/tile, UNIFORM vmcnt(6).
// Regions: Ap0 = subs{sub&4==0} (per-wave m-frags 0,1), Ap1 = rest, B = all 16 subs.
// Stage schedule: p1(kt) stages Ap0(kt+2)+B(kt+2) [4 loads]; p0(kt) stages Ap1(kt+1) [2].
// Death audit: p1 stages regions read only in p0 (same tile, reads drained by p0's
// lgkmcnt(0)+barrier); p0 stages Ap1 of the OTHER buffer whose reads ended in p1(kt-1).
// Ledger (6 loads/tile, order [Ap0,B | Ap1]): end-p0 wait vmcnt(6), end-p1 wait vmcnt(6),
// prologue vmcnt(6).
__global__ __launch_bounds__(512, 2) void gemm2p(const __bf16* __restrict__ A,
                                                 const __bf16* __restrict__ Bt,
                                                 float* __restrict__ C,
                                                 int M, int N, int K) {
  constexpr int ABYTES = 256 * 64 * 2;   // 32 KB
  constexpr int BBYTES = 128 * 64 * 2;   // 16 KB
  __shared__ alignas(1024) char smem[2 * (ABYTES + BBYTES)];  // 96 KB

  const int tid = threadIdx.x;
  const int l = tid & 63, w = tid >> 6;
  const int wr = w >> 1, wc = w & 1;
  const int g = l >> 4, ln = l & 15;

  const int nbx = gridDim.x;  // 16
  const int nwg = nbx * gridDim.y;
  int lin = blockIdx.y * nbx + blockIdx.x;
  lin = (lin & 7) * (nwg >> 3) + (lin >> 3);  // bijective: 256 % 8 == 0
  const int brow = (lin / nbx) * 256, bcol = (lin % nbx) * 128;

  const __bf16* Ag = A + (size_t)brow * K;
  const __bf16* Bg = Bt + (size_t)bcol * K;
  const int NT = K / 64;  // 32

  auto Abuf = [&](int buf) -> char* { return smem + buf * ABYTES; };
  auto Bbuf = [&](int buf) -> char* { return smem + 2 * ABYTES + buf * BBYTES; };

  f32x4 acc[4][4] = {};

  auto chunk = [&](const __bf16* gb, char* lb, int ktc, int sub) {
    int r16 = l >> 2;
    int colb = ((l & 3) * 16) ^ (((l >> 5) & 1) << 5);
    int row = (sub >> 1) * 16 + r16;
    gload_lds16(gb + (size_t)row * K + ktc * 64 + (sub & 1) * 32 + (colb >> 1),
                lb + sub * 1024 + l * 16);
  };
  auto stAp0 = [&](int ktc, int buf) {  // subs with sub&4==0 (16 subs, 2/thr)
    #pragma unroll
    for (int i = 0; i < 2; ++i) { int t = i * 8 + w; chunk(Ag, Abuf(buf), ktc, (t >> 2) * 8 + (t & 3)); }
  };
  auto stAp1 = [&](int ktc, int buf) {  // subs with sub&4==4 (16 subs, 2/thr)
    #pragma unroll
    for (int i = 0; i < 2; ++i) { int t = i * 8 + w; chunk(Ag, Abuf(buf), ktc, (t >> 2) * 8 + 4 + (t & 3)); }
  };
  auto stB = [&](int ktc, int buf) {  // 16 subs, 2/thr
    #pragma unroll
    for (int i = 0; i < 2; ++i) { int t = i * 8 + w; chunk(Bg, Bbuf(buf), ktc, t); }
  };

  auto ldA = [&](int buf, int mi, int kk) -> bf16x8 {
    int sub = (wr * 4 + mi) * 2 + kk;
    return *(const bf16x8*)(Abuf(buf) + sub * 1024 + ln * 64 + ((g * 16) ^ (((ln >> 3) & 1) << 5)));
  };
  auto ldB = [&](int buf, int nf, int kk) -> bf16x8 {
    int sub = (wc * 4 + nf) * 2 + kk;
    return *(const bf16x8*)(Bbuf(buf) + sub * 1024 + ln * 64 + ((g * 16) ^ (((ln >> 3) & 1) << 5)));
  };

  auto vm6 = [&]() {
    asm volatile("s_waitcnt vmcnt(6)" ::: "memory");
    __builtin_amdgcn_sched_barrier(0);
  };
  auto bar = [&]() {
    __builtin_amdgcn_sched_barrier(0);
    __builtin_amdgcn_s_barrier();
    __builtin_amdgcn_sched_barrier(0);
  };

  // prologue: Ap0(0),B(0) | Ap1(0) | Ap0(1),B(1)   (p0(0) will stage Ap1(1))
  stAp0(0, 0); stB(0, 0);
  stAp1(0, 0);
  stAp0(1, 1); stB(1, 1);
  vm6();
  bar();

  bf16x8 af[2][2], bfv[4][2];

  for (int kt = 0; kt < NT; ++kt) {
    const int buf = kt & 1;
    const int ktc1 = (kt + 1) & 31;  // Ap1 target (buf^1)
    const int ktc2 = (kt + 2) & 31;  // Ap0/B target (buf)

    // ---- p0: read Ap0-frags (mi 0,1) + all B; stage Ap1(kt+1) into buf^1; MFMA 16 ----
    #pragma unroll
    for (int mi = 0; mi < 2; ++mi) { af[mi][0] = ldA(buf, mi, 0); af[mi][1] = ldA(buf, mi, 1); }
    #pragma unroll
    for (int nf = 0; nf < 4; ++nf) { bfv[nf][0] = ldB(buf, nf, 0); bfv[nf][1] = ldB(buf, nf, 1); }
    stAp1(ktc1, buf ^ 1);
    bar();
    lgkm0_sb();
    __builtin_amdgcn_s_setprio(1);
    #pragma unroll
    for (int mi = 0; mi < 2; ++mi)
      #pragma unroll
      for (int nf = 0; nf < 4; ++nf)
        #pragma unroll
        for (int kk = 0; kk < 2; ++kk)
          acc[mi][nf] = __builtin_amdgcn_mfma_f32_16x16x32_bf16(af[mi][kk], bfv[nf][kk], acc[mi][nf], 0, 0, 0);
    __builtin_amdgcn_s_setprio(0);
    vm6();
    bar();

    // ---- p1: read Ap1-frags (mi 2,3); stage Ap0(kt+2)+B(kt+2) into buf; MFMA 16 ----
    #pragma unroll
    for (int mi = 0; mi < 2; ++mi) { af[mi][0] = ldA(buf, 2 + mi, 0); af[mi][1] = ldA(buf, 2 + mi, 1); }
    stAp0(ktc2, buf); stB(ktc2, buf);
    bar();
    lgkm0_sb();
    __builtin_amdgcn_s_setprio(1);
    #pragma unroll
    for (int mi = 0; mi < 2; ++mi)
      #pragma unroll
      for (int nf = 0; nf < 4; ++nf)
        #pragma unroll
        for (int kk = 0; kk < 2; ++kk)
          acc[2 + mi][nf] = __builtin_amdgcn_mfma_f32_16x16x32_bf16(af[mi][kk], bfv[nf][kk], acc[2 + mi][nf], 0, 0, 0);
    __builtin_amdgcn_s_setprio(0);
    vm6();
    bar();
  }

  // epilogue: C/D layout col=lane&15, row=(lane>>4)*4+j
  #pragma unroll
  for (int mi = 0; mi < 4; ++mi)
    #pragma unroll
    for (int nf = 0; nf < 4; ++nf)
      #pragma unroll
      for (int j = 0; j < 4; ++j) {
        size_t r = brow + wr * 64 + mi * 16 + g * 4 + j;
        size_t c = bcol + wc * 64 + nf * 16 + ln;
        C[r * N + c] = acc[mi][nf][j];
      }
}

// ---------------- RoPE in place on K columns of QKV [4096][3072] ----------------
__global__ void ropek_kernel(__bf16* __restrict__ QKV, const float* __restrict__ cosb,
                             const float* __restrict__ sinb) {
  int gid = blockIdx.x * 256 + threadIdx.x;  // total 4096*4*16
  int p = gid & 15;
  int ht = gid >> 4;
  int hc = ht & 3;
  int tok = ht >> 2;
  int s = tok & 1023;
  __bf16* base = QKV + (size_t)tok * 3072 + 2048 + hc * 128;
  int d0 = p * 4;
  const float* cr = cosb + s * 128;
  const float* sr = sinb + s * 128;
  float x0[4], x1[4];
  #pragma unroll
  for (int j = 0; j < 4; ++j) {
    x0[j] = (float)base[d0 + j];
    x1[j] = (float)base[d0 + 64 + j];
  }
  #pragma unroll
  for (int j = 0; j < 4; ++j) {
    float n0 = x0[j] * cr[d0 + j] - x1[j] * sr[d0 + j];
    float n1 = x1[j] * cr[d0 + 64 + j] + x0[j] * sr[d0 + 64 + j];
    base[d0 + j] = (__bf16)n0;
    base[d0 + 64 + j] = (__bf16)n1;
  }
}

// ---------------- Flash attention (causal, GQA) — transposed orientation, fused Q-RoPE ----------------
__global__ __launch_bounds__(256, 2) void attn_kernel(const __bf16* __restrict__ QKV,
                                                      const __bf16* __restrict__ VT,
                                                      const float* __restrict__ cosb,
                                                      const float* __restrict__ sinb,
                                                      __bf16* __restrict__ AO) {
  __shared__ __bf16 Kl[2][64 * 128];
  __shared__ __bf16 Vt[128 * 64];
  __shared__ __bf16 Pl[4][16 * 72];

  const int tid = threadIdx.x, l = tid & 63, w = tid >> 6;
  const int h = blockIdx.y, b = blockIdx.z;
  const int kvh = h >> 2;
  const int g = l >> 4, ln = l & 15;
  const __bf16* VTg = VT + (size_t)(b * 4 + kvh) * 128 * 1024;
  const float scsc = 0.08838834764831845f;  // 1/sqrt(128)

  auto stageK = [&](int buf, int kt) {
    const __bf16* Kg = QKV + (size_t)(b * 1024 + kt * 64) * 3072 + 2048 + kvh * 128;
    #pragma unroll
    for (int i = 0; i < 4; ++i) {
      int r = i * 16 + (tid >> 4);
      int c = tid & 15;
      int csw = c ^ (r & 7);
      gload_lds16(Kg + (size_t)r * 3072 + csw * 8, (char*)&Kl[buf][0] + i * 4096 + tid * 16);
    }
  };
  auto stageV = [&](int kt) {
    #pragma unroll
    for (int i = 0; i < 4; ++i) {
      int ci = i * 256 + tid;
      int row = ci >> 3;
      int c = ci & 7;
      int csw = c ^ (row & 7);
      gload_lds16(VTg + (size_t)row * 1024 + kt * 64 + csw * 8, (char*)Vt + (size_t)ci * 16);
    }
  };

  #pragma unroll 1
  for (int pass = 0; pass < 2; ++pass) {
    const int qt = pass ? 15 - (int)blockIdx.x : (int)blockIdx.x;
    const size_t tokQ = (size_t)b * 1024 + qt * 64;
    const int srow = qt * 64 + w * 16 + ln;  // seq position of this lane's q-row

    // Q fragments + in-register RoPE: d = ks*32 + g*8 + j; pair (d, d+64) lives
    // in (ks, ks+2); cos/sin tables satisfy c[d+64]=c[d].
    bf16x8 qf[4];
    {
      const __bf16* qp = QKV + (tokQ + w * 16 + ln) * 3072 + h * 128;
      bf16x8 qraw[4];
      #pragma unroll
      for (int ks = 0; ks < 4; ++ks) qraw[ks] = *(const bf16x8*)(qp + ks * 32 + g * 8);
      const float* cr = cosb + (size_t)srow * 128;
      const float* sr = sinb + (size_t)srow * 128;
      #pragma unroll
      for (int ks2 = 0; ks2 < 2; ++ks2)
        #pragma unroll
        for (int j = 0; j < 8; ++j) {
          int d = ks2 * 32 + g * 8 + j;  // < 64
          float lo = (float)qraw[ks2][j], hi = (float)qraw[ks2 + 2][j];
          float c0 = cr[d], s0 = sr[d];
          qf[ks2][j]     = (__bf16)(lo * c0 - hi * s0);
          qf[ks2 + 2][j] = (__bf16)(hi * c0 + lo * s0);
        }
    }

    float mrow = -1e30f, lrow = 0.f;
    f32x4 acco[8] = {};

    stageK(0, 0);
    int cur = 0;

    for (int kt = 0; kt <= qt; ++kt) {
      __syncthreads();

      stageV(kt);
      if (kt < qt) stageK(cur ^ 1, kt + 1);

      f32x4 accs[4] = {};
      __builtin_amdgcn_s_setprio(1);
      #pragma unroll
      for (int cb = 0; cb < 4; ++cb) {
        int row = cb * 16 + ln;
        #pragma unroll
        for (int ks = 0; ks < 4; ++ks) {
          bf16x8 kb = *(const bf16x8*)((const char*)&Kl[cur][0] + row * 256 +
                                       (((ks * 4 + g) ^ (row & 7)) * 16));
          accs[cb] = __builtin_amdgcn_mfma_f32_16x16x32_bf16(kb, qf[ks], accs[cb], 0, 0, 0);
        }
      }
      __builtin_amdgcn_s_setprio(0);

      const bool diag = (kt == qt);
      #pragma unroll
      for (int cb = 0; cb < 4; ++cb)
        #pragma unroll
        for (int j = 0; j < 4; ++j) {
          float s = accs[cb][j] * scsc;
          if (diag && (cb * 16 + g * 4 + j > w * 16 + ln)) s = -1e30f;
          accs[cb][j] = s;
        }

      float mt = accs[0][0];
      #pragma unroll
      for (int cb = 0; cb < 4; ++cb)
        #pragma unroll
        for (int j = 0; j < 4; ++j) mt = fmaxf(mt, accs[cb][j]);
      mt = fmaxf(mt, __shfl_xor(mt, 16, 64));
      mt = fmaxf(mt, __shfl_xor(mt, 32, 64));
      float mnew = fmaxf(mrow, mt);
      float corr = __expf(mrow - mnew);
      mrow = mnew;
      float rs = 0.f;
      #pragma unroll
      for (int cb = 0; cb < 4; ++cb)
        #pragma unroll
        for (int j = 0; j < 4; ++j) {
          float p = __expf(accs[cb][j] - mnew);
          accs[cb][j] = p;
          rs += p;
        }
      rs += __shfl_xor(rs, 16, 64);
      rs += __shfl_xor(rs, 32, 64);
      lrow = lrow * corr + rs;
      #pragma unroll
      for (int n = 0; n < 8; ++n)
        #pragma unroll
        for (int j = 0; j < 4; ++j) acco[n][j] *= corr;

      #pragma unroll
      for (int cb = 0; cb < 4; ++cb) {
        bf16x4 pw;
        #pragma unroll
        for (int j = 0; j < 4; ++j) pw[j] = (__bf16)accs[cb][j];
        *(bf16x4*)(&Pl[w][ln * 72 + cb * 16 + g * 4]) = pw;
      }

      __syncthreads();

      __builtin_amdgcn_s_setprio(1);
      #pragma unroll
      for (int sc = 0; sc < 2; ++sc) {
        bf16x8 pa = *(const bf16x8*)(&Pl[w][ln * 72 + sc * 32 + g * 8]);
        #pragma unroll
        for (int n = 0; n < 8; ++n) {
          int row = n * 16 + ln;
          bf16x8 vb = *(const bf16x8*)((const char*)Vt + row * 128 +
                                       (((sc * 4 + g) ^ (row & 7)) * 16));
          acco[n] = __builtin_amdgcn_mfma_f32_16x16x32_bf16(vb, pa, acco[n], 0, 0, 0);
        }
      }
      __builtin_amdgcn_s_setprio(0);
      cur ^= 1;
    }

    float rl = 1.f / lrow;
    size_t r = tokQ + w * 16 + ln;
    #pragma unroll
    for (int n = 0; n < 8; ++n) {
      bf16x4 ov;
      #pragma unroll
      for (int j = 0; j < 4; ++j) ov[j] = (__bf16)(acco[n][j] * rl);
      *(bf16x4*)(&AO[r * 2048 + h * 128 + n * 16 + g * 4]) = ov;
    }
  }
}

// ---------------- launch ----------------
extern "C" void kernel_launch(void* const* d_in, const int* in_sizes, int n_in,
                              void* d_out, int out_size, void* d_ws, size_t ws_size,
                              hipStream_t stream) {
  const float* x    = (const float*)d_in[0];
  const float* cosb = (const float*)d_in[1];
  const float* sinb = (const float*)d_in[2];
  const float* wq   = (const float*)d_in[3];
  const float* wk   = (const float*)d_in[4];
  const float* wv   = (const float*)d_in[5];
  const float* wo   = (const float*)d_in[6];
  float* out = (float*)d_out;

  char* ws = (char*)d_ws;
  const size_t OFF_XB    = 0;                       // 4096*2048 bf16 = 16 MiB (dead after gemm#1)
  const size_t OFF_WQKVT = OFF_XB + 16777216;       // 3072*2048 bf16 = 12 MiB
  const size_t OFF_WOT   = OFF_WQKVT + 12582912;    // 2048*2048 bf16 = 8 MiB
  const size_t OFF_QKV   = OFF_WOT + 8388608;       // 4096*3072 bf16 = 24 MiB
  const size_t OFF_AO    = OFF_QKV + 25165824;      // 4096*2048 bf16 = 16 MiB
  const size_t OFF_VT    = OFF_XB;                  // 16*128*1024 bf16 = 4 MiB, aliases Xb

  __bf16* Xb    = (__bf16*)(ws + OFF_XB);
  __bf16* WqkvT = (__bf16*)(ws + OFF_WQKVT);
  __bf16* WoT   = (__bf16*)(ws + OFF_WOT);
  __bf16* QKVb  = (__bf16*)(ws + OFF_QKV);
  __bf16* AOb   = (__bf16*)(ws + OFF_AO);
  __bf16* VTb   = (__bf16*)(ws + OFF_VT);

  // 1. convert x
  cvt_kernel<<<4096 * 2048 / 8 / 256, 256, 0, stream>>>(x, Xb, 4096 * 2048);
  // 2. transpose-convert weights
  tcvt_kernel<<<dim3(64, 64), 256, 0, stream>>>(wq, WqkvT, 2048, 2048);
  tcvt_kernel<<<dim3(16, 64), 256, 0, stream>>>(wk, WqkvT + (size_t)2048 * 2048, 2048, 512);
  tcvt_kernel<<<dim3(16, 64), 256, 0, stream>>>(wv, WqkvT + (size_t)2560 * 2048, 2048, 512);
  tcvt_kernel<<<dim3(64, 64), 256, 0, stream>>>(wo, WoT, 2048, 2048);
  // 3. QKV projection: 256x192 tiles, 16x16 = 256 blocks (full chip fill)
  gemm8p_qkv<<<dim3(16, 16), 512, 0, stream>>>(Xb, WqkvT, QKVb, 4096, 3072, 2048);
  // 4. transpose V into VT (V is not RoPE'd)
  vt_kernel<<<dim3(32, 4, 16), 256, 0, stream>>>(QKVb, VTb);
  // 5. RoPE K only (Q-rope fused into attention)
  ropek_kernel<<<4096 * 4 * 16 / 256, 256, 0, stream>>>(QKVb, cosb, sinb);
  // 6. attention: Q-tile 64, balanced pairs (x, 15-x), fused Q-RoPE
  attn_kernel<<<dim3(8, 16, 4), 256, 0, stream>>>(QKVb, VTb, cosb, sinb, AOb);
  // 7. output projection: 256x128 tiles, 16x16 = 256 blocks (full fill, 2-phase)
  gemm2p<<<dim3(16, 16), 512, 0, stream>>>(AOb, WoT, out, 4096, 2048, 2048);
}